// Round 7
// baseline (1117.589 us; speedup 1.0000x reference)
//
#include <hip/hip_runtime.h>
#include <math.h>

#define BATCH 512
#define NG 16
#define GSZ 32
#define H 128
#define E 64
#define PRE 512
#define BOT 1024
#define MLPD 1024
#define SEQ 12
#define AK 1152   // Abf row length = H + BOT

typedef __attribute__((ext_vector_type(8))) short bf16x8;
typedef __attribute__((ext_vector_type(4))) float f32x4;

union bf8pack { ushort s[8]; uint4 v; };

__device__ __forceinline__ unsigned short f2bf(float f) {
    unsigned u = __float_as_uint(f);
    u += 0x7FFF + ((u >> 16) & 1);   // round-to-nearest-even
    return (unsigned short)(u >> 16);
}
__device__ __forceinline__ float bf2f(unsigned short s) {
    return __uint_as_float(((unsigned)s) << 16);
}

#define GLB(p) ((const __attribute__((address_space(1))) unsigned int*)(p))
#define LDS(p) ((__attribute__((address_space(3))) unsigned int*)(p))

// ---------------------------------------------------------------- one-shot prep
#define N0 (BOT * PRE)        /* W2b   */
#define N1 (MLPD * AK)        /* Wm1pk: MFMA-fragment-packed Wm1 (R7) */
#define N2 (H * MLPD)         /* Wm2pk: MFMA-fragment-packed Wm2 (R7) */
#define N3 (PRE * H)          /* W1pk: MFMA-fragment-packed W1[:,64:192] (R4) */
#define N4 (PRE)              /* wc    */
#define N5 (BATCH * H)        /* c     */
#define N5b (BATCH * H)       /* h0 = hh */
#define N6 (BATCH * 2)        /* pos   */
#define N7 (512 * 128)        /* Whpk: MFMA-fragment-packed Whh (R4) */
#define N8 (512)              /* Wx0/Wx1/bx: rank-2 fold of dec_in@Wih^T (R3) */
#define PREP_TOT (N0 + N1 + N2 + N3 + N4 + N5 + N5b + N6 + N7 + N8 + 1)

__global__ void prep_kernel(
    const float* __restrict__ W2, const float* __restrict__ Wm1,
    const float* __restrict__ Wm2, const float* __restrict__ W1,
    const float* __restrict__ Wp, const float* __restrict__ bp, const float* __restrict__ b1,
    const float* __restrict__ ch, const float* __restrict__ hh, const float* __restrict__ last_pos,
    const float* __restrict__ Wih, const float* __restrict__ Whh,
    const float* __restrict__ bih, const float* __restrict__ bhh,
    const float* __restrict__ Wse, const float* __restrict__ bse,
    unsigned short* __restrict__ W2b, unsigned short* __restrict__ Wm1pk,
    unsigned short* __restrict__ Wm2pk, unsigned short* __restrict__ W1pk,
    float* __restrict__ Wcx, float* __restrict__ Wcy, float* __restrict__ biash,
    float* __restrict__ cbuf, float* __restrict__ hbuf, float* __restrict__ pos,
    unsigned short* __restrict__ Whpk,
    float* __restrict__ Wx0, float* __restrict__ Wx1, float* __restrict__ bx,
    float* __restrict__ loss)
{
    long idx = (long)blockIdx.x * 256 + threadIdx.x;
    if (idx < N0) { W2b[idx] = f2bf(W2[idx]); return; }
    idx -= N0;
    if (idx < N1) {
        // Wm1pk[(((ni*8+w)*36+ks)*64+lane)*8+e] = Wm1[col*1152 + k]
        //   col = ni*128 + w*16 + (lane&15), k = ks*32 + (lane>>4)*8 + e
        int e = (int)(idx & 7);
        long u = idx >> 3;
        int lane = (int)(u & 63);
        long rest = u >> 6;                 // 0 .. 2303
        int ks = (int)(rest % 36);
        int r2 = (int)(rest / 36);          // 0 .. 63
        int w = r2 & 7, ni = r2 >> 3;
        int col = ni * 128 + w * 16 + (lane & 15);
        int k = ks * 32 + (lane >> 4) * 8 + e;
        Wm1pk[idx] = f2bf(Wm1[(size_t)col * AK + k]);
        return;
    }
    idx -= N1;
    if (idx < N2) {
        // Wm2pk[((w*32+ks)*64+lane)*8+e] = Wm2[col*1024 + k]
        //   col = w*16 + (lane&15), k = ks*32 + (lane>>4)*8 + e
        int e = (int)(idx & 7);
        long u = idx >> 3;
        int lane = (int)(u & 63);
        int rest = (int)(u >> 6);           // 0 .. 255
        int ks = rest & 31, w = rest >> 5;
        int col = w * 16 + (lane & 15);
        int k = ks * 32 + (lane >> 4) * 8 + e;
        Wm2pk[idx] = f2bf(Wm2[(size_t)col * MLPD + k]);
        return;
    }
    idx -= N2;
    if (idx < N3) {
        // W1pk[(((w*4+ks)*4+nt)*4+quad)*16 + l16][e] = W1[col*192 + 64 + k]
        int e = (int)(idx & 7);
        int u = (int)(idx >> 3);
        int l16 = u & 15, quad = (u >> 4) & 3, nt = (u >> 6) & 3, ks = (u >> 8) & 3, w = u >> 10;
        int col = w * 64 + nt * 16 + l16;
        int k = ks * 32 + quad * 8 + e;
        W1pk[idx] = f2bf(W1[col * 192 + E + k]);
        return;
    }
    idx -= N3;
    if (idx < N4) {
        int p = (int)idx;
        float sx = 0.f, sy = 0.f, sb = 0.f;
#pragma unroll 8
        for (int e = 0; e < E; ++e) {
            float w = W1[p * 192 + e];
            sx += w * Wp[e * 2 + 0];
            sy += w * Wp[e * 2 + 1];
            sb += w * bp[e];
        }
        Wcx[p] = sx; Wcy[p] = sy; biash[p] = b1[p] + sb;
        return;
    }
    idx -= N4;
    if (idx < N5) { cbuf[idx] = ch[idx]; return; }
    idx -= N5;
    if (idx < N5b) { hbuf[idx] = hh[idx]; return; }
    idx -= N5b;
    if (idx < N6) { pos[idx] = last_pos[idx]; return; }
    idx -= N6;
    if (idx < N7) {
        // Whpk[(((g*8+w)*4+ks)*4+quad)*16 + l16][e] = Whh[col*128 + k]
        int e = (int)(idx & 7);
        int u = (int)(idx >> 3);
        int l16 = u & 15, quad = (u >> 4) & 3, ks = (u >> 6) & 3, w = (u >> 8) & 7, g = u >> 11;
        int col = g * 128 + w * 16 + l16;
        int k = ks * 32 + quad * 8 + e;
        Whpk[idx] = f2bf(Whh[col * H + k]);
        return;
    }
    idx -= N7;
    if (idx < N8) {
        int u = (int)idx;
        float sx = 0.f, sy = 0.f, sb = 0.f;
#pragma unroll 8
        for (int e = 0; e < E; ++e) {
            float w = Wih[u * E + e];
            sx += w * Wse[e * 2 + 0];
            sy += w * Wse[e * 2 + 1];
            sb += w * bse[e];
        }
        Wx0[u] = sx; Wx1[u] = sy; bx[u] = sb + bih[u] + bhh[u];
        return;
    }
    idx -= N8;
    if (idx == 0) *loss = 0.0f;
}

// ---------------------------------------------------------------- fused LSTM + Hpart
// R2: 32 blocks x 512 threads, 16 rows/block, 8 waves.
// R3: dec_in@Wih^T folded to rank-2 -> gate GEMM K=128.
// R4: B-operands pre-packed in MFMA fragment order (base + lane*16B loads).
#define LROWS 16
__global__ __launch_bounds__(512) void lstm_hpart(
    int t,
    const float* __restrict__ relin, const float* __restrict__ gt,
    const unsigned short* __restrict__ Whpk,
    const float* __restrict__ Wx0, const float* __restrict__ Wx1, const float* __restrict__ bx,
    const float* __restrict__ Wpos, const float* __restrict__ bpos,
    const unsigned short* __restrict__ W1pk, const float* __restrict__ biash,
    const float* __restrict__ hbuf, float* __restrict__ cbuf,
    unsigned short* __restrict__ Abf, float* __restrict__ Hpartf,
    float* __restrict__ pos, float* __restrict__ traj, float* __restrict__ loss)
{
    constexpr int LDHB = 136;
    constexpr int LDHF = 129;
    __shared__ __align__(16) unsigned short As[LROWS * LDHB];
    __shared__ __align__(16) unsigned short hnb[LROWS * LDHB];
    __shared__ float hnf[LROWS * LDHF];
    const int r0 = blockIdx.x * LROWS;     // global row base
    const int tid = threadIdx.x;
    const int lane = tid & 63, w = tid >> 6;          // w in 0..7
    const int quad = lane >> 4, l16 = lane & 15;

    // ---- build A = bf16(h_in) : 16 x 128 ----
    for (int idx = tid; idx < LROWS * H; idx += 512) {
        int row = idx >> 7, k = idx & 127;
        As[row * LDHB + k] = f2bf(hbuf[(size_t)(r0 + row) * H + k]);
    }
    __syncthreads();

    // ---- gate GEMM (K=128): wave w -> u-slice [w*16, w*16+16), all 4 gates ----
    f32x4 acc[4];
#pragma unroll
    for (int g4 = 0; g4 < 4; ++g4) acc[g4] = (f32x4)0.f;
#pragma unroll
    for (int ks = 0; ks < 4; ++ks) {
        bf16x8 af = *(const bf16x8*)&As[l16 * LDHB + ks * 32 + quad * 8];
#pragma unroll
        for (int gate = 0; gate < 4; ++gate) {
            bf16x8 bf = *(const bf16x8*)&Whpk[((size_t)((gate * 8 + w) * 4 + ks) * 64 + lane) * 8];
            acc[gate] = __builtin_amdgcn_mfma_f32_16x16x32_bf16(af, bf, acc[gate], 0, 0, 0);
        }
    }

    // ---- nonlinearity + c update (u = w*16 + l16, rows = quad*4+r) ----
    {
        int u = w * 16 + l16;
        float wx0[4], wx1[4], bxv[4];
#pragma unroll
        for (int gate = 0; gate < 4; ++gate) {
            int col = gate * 128 + u;
            wx0[gate] = Wx0[col]; wx1[gate] = Wx1[col]; bxv[gate] = bx[col];
        }
#pragma unroll
        for (int r = 0; r < 4; ++r) {
            int row = quad * 4 + r;
            int b = r0 + row;
            float rx = relin[b * 2 + 0], ry = relin[b * 2 + 1];
            float i_ = acc[0][r] + rx * wx0[0] + ry * wx1[0] + bxv[0];
            float f_ = acc[1][r] + rx * wx0[1] + ry * wx1[1] + bxv[1];
            float g_ = acc[2][r] + rx * wx0[2] + ry * wx1[2] + bxv[2];
            float o_ = acc[3][r] + rx * wx0[3] + ry * wx1[3] + bxv[3];
            float ig = 1.0f / (1.0f + expf(-i_));
            float fg = 1.0f / (1.0f + expf(-f_));
            float gg = tanhf(g_);
            float og = 1.0f / (1.0f + expf(-o_));
            float c = fg * cbuf[(size_t)b * H + u] + ig * gg;
            cbuf[(size_t)b * H + u] = c;
            float h = og * tanhf(c);
            hnb[row * LDHB + u] = f2bf(h);
            hnf[row * LDHF + u] = h;
            Abf[(size_t)b * AK + u] = f2bf(h);
        }
    }
    __syncthreads();

    // ---- Hpart GEMM (dead at last step): wave w -> cols [w*64, w*64+64) ----
    if (t < SEQ - 1) {
        f32x4 acc2[4];
#pragma unroll
        for (int nt = 0; nt < 4; ++nt) acc2[nt] = (f32x4)0.f;
#pragma unroll
        for (int ks = 0; ks < 4; ++ks) {
            bf16x8 af = *(const bf16x8*)&hnb[l16 * LDHB + ks * 32 + quad * 8];
#pragma unroll
            for (int nt = 0; nt < 4; ++nt) {
                bf16x8 bfr = *(const bf16x8*)&W1pk[((size_t)((w * 4 + ks) * 4 + nt) * 64 + lane) * 8];
                acc2[nt] = __builtin_amdgcn_mfma_f32_16x16x32_bf16(af, bfr, acc2[nt], 0, 0, 0);
            }
        }
#pragma unroll
        for (int nt = 0; nt < 4; ++nt) {
            int col = w * 64 + nt * 16 + l16;
            float bv = biash[col];
#pragma unroll
            for (int r = 0; r < 4; ++r) {
                int row = quad * 4 + r;
                Hpartf[(size_t)(r0 + row) * PRE + col] = acc2[nt][r] + bv;
            }
        }
    }

    // ---- rel_pos / curr_pos / traj / loss — 512 threads, 16-seg shfl reduce ----
    {
        int row = tid >> 5, o = (tid >> 4) & 1, seg = tid & 15;
        const float* wr = Wpos + o * H + seg * 8;
        const float* hr = &hnf[row * LDHF + seg * 8];
        float acc3 = 0.f;
#pragma unroll
        for (int k = 0; k < 8; ++k) acc3 += wr[k] * hr[k];
        acc3 += __shfl_xor(acc3, 1);
        acc3 += __shfl_xor(acc3, 2);
        acc3 += __shfl_xor(acc3, 4);
        acc3 += __shfl_xor(acc3, 8);
        if (seg == 0) {
            acc3 += bpos[o];
            int b = r0 + row;
            float lp = pos[b * 2 + o];
            pos[b * 2 + o] = acc3 + lp;
            traj[b * 2 + o] = acc3;
            float d = acc3 - gt[b * 2 + o];
            atomicAdd(loss, d * d * (1.0f / 1024.0f));
        }
    }
}

// ---------------------------------------------------------------- fused MLP (R7): dh = relu(A@Wm1^T+bm1); h = relu(dh@Wm2^T+bm2)
// 32 blocks x 512 thr (8 waves), 16 rows/block. dh lives only in LDS (no dhbf
// round-trip, one launch instead of two). Wm1pk/Wm2pk are fragment-packed ->
// every B load is base + lane*16B, no LDS staging for weights.
__global__ __launch_bounds__(512) void mlp_fused(
    const unsigned short* __restrict__ Abf,
    const unsigned short* __restrict__ Wm1pk, const float* __restrict__ bm1,
    const unsigned short* __restrict__ Wm2pk, const float* __restrict__ bm2,
    float* __restrict__ hbuf)
{
    constexpr int LDA1 = 1160;   // 1152+8: rows 16B-aligned, banks spread
    constexpr int LDD  = 1032;   // 1024+8
    __shared__ __align__(16) unsigned short As[16 * LDA1];  // 37.1 KB
    __shared__ __align__(16) unsigned short dh[16 * LDD];   // 33 KB
    const int tid = threadIdx.x;
    const int lane = tid & 63, w = tid >> 6;
    const int quad = lane >> 4, l16 = lane & 15;
    const int r0 = blockIdx.x * 16;

    // ---- stage A: 16 rows x 1152 bf16 (uint4 = 8 elems) ----
    for (int e = tid; e < 16 * 144; e += 512) {
        int row = e / 144, q = e - row * 144;
        *(uint4*)&As[row * LDA1 + q * 8] = *(const uint4*)&Abf[(size_t)(r0 + row) * AK + q * 8];
    }
    __syncthreads();

    // ---- phase 1: dh[16][1024], wave w owns cols {ni*128 + w*16 + l16} ----
    f32x4 acc[8];
#pragma unroll
    for (int ni = 0; ni < 8; ++ni) acc[ni] = (f32x4)0.f;
    for (int ks = 0; ks < 36; ++ks) {
        bf16x8 af = *(const bf16x8*)&As[l16 * LDA1 + ks * 32 + quad * 8];
#pragma unroll
        for (int ni = 0; ni < 8; ++ni) {
            bf16x8 bf = *(const bf16x8*)&Wm1pk[(((size_t)(ni * 8 + w) * 36 + ks) * 64 + lane) * 8];
            acc[ni] = __builtin_amdgcn_mfma_f32_16x16x32_bf16(af, bf, acc[ni], 0, 0, 0);
        }
    }
#pragma unroll
    for (int ni = 0; ni < 8; ++ni) {
        int col = ni * 128 + w * 16 + l16;
        float bv = bm1[col];
#pragma unroll
        for (int r = 0; r < 4; ++r)
            dh[(quad * 4 + r) * LDD + col] = f2bf(fmaxf(acc[ni][r] + bv, 0.f));
    }
    __syncthreads();

    // ---- phase 2: h[16][128], wave w owns cols {w*16 + l16} ----
    f32x4 acc2 = (f32x4)0.f;
#pragma unroll 8
    for (int ks = 0; ks < 32; ++ks) {
        bf16x8 af = *(const bf16x8*)&dh[l16 * LDD + ks * 32 + quad * 8];
        bf16x8 bf = *(const bf16x8*)&Wm2pk[(((size_t)w * 32 + ks) * 64 + lane) * 8];
        acc2 = __builtin_amdgcn_mfma_f32_16x16x32_bf16(af, bf, acc2, 0, 0, 0);
    }
    {
        int col = w * 16 + l16;
        float bv = bm2[col];
#pragma unroll
        for (int r = 0; r < 4; ++r)
            hbuf[(size_t)(r0 + quad * 4 + r) * H + col] = fmaxf(acc2[r] + bv, 0.f);
    }
}

// ---------------------------------------------------------------- fused x1-build + pool GEMM + max_j (R5/R6)
// A-tile (128 rows = 4 i x 32 j of one group) built in LDS from Hpart/pos/Wc*
// each K-step (2x redundant across 2 n-tiles). BN=512, 8 waves, 82KB LDS, 1 blk/CU.
__global__ __launch_bounds__(512) void pool_fused(
    const float* __restrict__ Hpartf, const float* __restrict__ pos,
    const float* __restrict__ Wcx, const float* __restrict__ Wcy,
    const unsigned short* __restrict__ W2b,
    const float* __restrict__ b2, unsigned short* __restrict__ Abf)
{
    constexpr int BN = 512;
    constexpr int LDA = 72;    // pad: row stride 144B -> 4-bank offset/row, 2-way (free)
    __shared__ __align__(16) unsigned short As[128 * LDA];   // 18 KB
    __shared__ __align__(16) unsigned short Bs[BN * 64];     // 64 KB
    const int tid = threadIdx.x;
    const int lane = tid & 63, w = tid >> 6;       // 8 waves
    const int quad = lane >> 4, l16 = lane & 15;
    const int n_tile = blockIdx.x, m_tile = blockIdx.y;
    const int g = m_tile >> 3, iq = m_tile & 7;
    const int n0 = n_tile * BN;

    // per-thread build coords (loop-invariant): thread -> (row, 16-col slab)
    const int brow = tid >> 2;                 // 0..127
    const int k8 = (tid & 3) * 16;             // col base within K-step
    const int bi = iq * 4 + (brow >> 5), bj = brow & 31;
    const float rx = pos[(g * GSZ + bj) * 2 + 0] - pos[(g * GSZ + bi) * 2 + 0];
    const float ry = pos[(g * GSZ + bj) * 2 + 1] - pos[(g * GSZ + bi) * 2 + 1];
    const float* hrow = &Hpartf[(size_t)(g * GSZ + bj) * PRE];

    f32x4 acc[8][4];
#pragma unroll
    for (int mt = 0; mt < 8; ++mt)
#pragma unroll
        for (int nt = 0; nt < 4; ++nt) acc[mt][nt] = (f32x4)0.f;

    for (int k0 = 0; k0 < PRE; k0 += 64) {
        // stage B: 512 rows x 64 cols bf16 = 64KB, 8 x global_load_lds/thread
#pragma unroll
        for (int it = 0; it < 8; ++it) {
            int c = it * 512 + tid;
            __builtin_amdgcn_global_load_lds(
                GLB(W2b + (size_t)(n0 + (c >> 3)) * PRE + k0 + (c & 7) * 8),
                LDS(&Bs[c * 8]), 16, 0, 0);
        }
        // build A: As[row][kk] = bf16(relu(Hpart[j][k0+kk] + rx*Wcx + ry*Wcy))
        {
            const float4* hp = (const float4*)(hrow + k0 + k8);
            const float4* wx = (const float4*)(Wcx + k0 + k8);
            const float4* wy = (const float4*)(Wcy + k0 + k8);
            bf8pack o[2];
#pragma unroll
            for (int q = 0; q < 2; ++q) {
                float4 ha = hp[q * 2], hb = hp[q * 2 + 1];
                float4 xa = wx[q * 2], xb = wx[q * 2 + 1];
                float4 ya = wy[q * 2], yb = wy[q * 2 + 1];
                o[q].s[0] = f2bf(fmaxf(ha.x + rx * xa.x + ry * ya.x, 0.f));
                o[q].s[1] = f2bf(fmaxf(ha.y + rx * xa.y + ry * ya.y, 0.f));
                o[q].s[2] = f2bf(fmaxf(ha.z + rx * xa.z + ry * ya.z, 0.f));
                o[q].s[3] = f2bf(fmaxf(ha.w + rx * xa.w + ry * ya.w, 0.f));
                o[q].s[4] = f2bf(fmaxf(hb.x + rx * xb.x + ry * yb.x, 0.f));
                o[q].s[5] = f2bf(fmaxf(hb.y + rx * xb.y + ry * yb.y, 0.f));
                o[q].s[6] = f2bf(fmaxf(hb.z + rx * xb.z + ry * yb.z, 0.f));
                o[q].s[7] = f2bf(fmaxf(hb.w + rx * xb.w + ry * yb.w, 0.f));
            }
            *(uint4*)&As[brow * LDA + k8] = o[0].v;
            *(uint4*)&As[brow * LDA + k8 + 8] = o[1].v;
        }
        __syncthreads();
#pragma unroll
        for (int ks = 0; ks < 2; ++ks) {
            bf16x8 bfr[4];
#pragma unroll
            for (int nt = 0; nt < 4; ++nt)
                bfr[nt] = *(const bf16x8*)&Bs[(w * 64 + nt * 16 + l16) * 64 + ks * 32 + quad * 8];
#pragma unroll
            for (int mt = 0; mt < 8; ++mt) {
                bf16x8 af = *(const bf16x8*)&As[(mt * 16 + l16) * LDA + ks * 32 + quad * 8];
#pragma unroll
                for (int nt = 0; nt < 4; ++nt)
                    acc[mt][nt] = __builtin_amdgcn_mfma_f32_16x16x32_bf16(af, bfr[nt], acc[mt][nt], 0, 0, 0);
            }
        }
        __syncthreads();
    }

    // ---- max over j: rows il*32..il*32+31 live in acc[2il..2il+1] x quad lanes ----
#pragma unroll
    for (int il = 0; il < 4; ++il)
#pragma unroll
    for (int nt = 0; nt < 4; ++nt) {
        float u = -1e30f;
#pragma unroll
        for (int p = 0; p < 2; ++p)
#pragma unroll
            for (int r = 0; r < 4; ++r) u = fmaxf(u, acc[il * 2 + p][nt][r]);
        u = fmaxf(u, __shfl_xor(u, 16));
        u = fmaxf(u, __shfl_xor(u, 32));
        if (lane < 16) {
            int col = n0 + w * 64 + nt * 16 + l16;
            int gu = m_tile * 4 + il;
            Abf[(size_t)gu * AK + H + col] = f2bf(fmaxf(u + b2[col], 0.f));
        }
    }
}

// ---------------------------------------------------------------- launch
extern "C" void kernel_launch(void* const* d_in, const int* in_sizes, int n_in,
                              void* d_out, int out_size, void* d_ws, size_t ws_size,
                              hipStream_t stream)
{
    const float* last_pos     = (const float*)d_in[0];
    const float* last_pos_rel = (const float*)d_in[1];
    const float* hh           = (const float*)d_in[2];
    const float* ch           = (const float*)d_in[3];
    const float* ptr_rel      = (const float*)d_in[4];
    const float* Wih  = (const float*)d_in[6];
    const float* Whh  = (const float*)d_in[7];
    const float* bih  = (const float*)d_in[8];
    const float* bhh  = (const float*)d_in[9];
    const float* Wse  = (const float*)d_in[10];
    const float* bse  = (const float*)d_in[11];
    const float* Wpos = (const float*)d_in[12];
    const float* bpos = (const float*)d_in[13];
    const float* Wp   = (const float*)d_in[14];
    const float* bp   = (const float*)d_in[15];
    const float* W1   = (const float*)d_in[16];
    const float* b1   = (const float*)d_in[17];
    const float* W2   = (const float*)d_in[18];
    const float* b2   = (const float*)d_in[19];
    const float* Wm1  = (const float*)d_in[20];
    const float* bm1  = (const float*)d_in[21];
    const float* Wm2  = (const float*)d_in[22];
    const float* bm2  = (const float*)d_in[23];

    float* ws     = (float*)d_ws;
    float* hbuf   = ws;                       // 65536
    float* cbuf   = hbuf + BATCH * H;         // 65536
    float* pos    = cbuf + BATCH * H;         // 1024 (padded)
    float* Hpartf = pos + 1024;               // 262144
    float* Wcx    = Hpartf + BATCH * PRE;     // 512
    float* Wcy    = Wcx + PRE;                // 512
    float* biash  = Wcy + PRE;                // 512
    float* bx     = biash + PRE;              // 512
    float* Wx0    = bx + 512;                 // 512
    float* Wx1    = Wx0 + 512;                // 512
    unsigned short* ub    = (unsigned short*)(Wx1 + 512);
    unsigned short* Abf   = ub;                         // 512*1152
    unsigned short* dhbf  = Abf + (size_t)BATCH * AK;   // 512*1024 (unused since R7; keeps layout)
    unsigned short* W2b   = dhbf + (size_t)BATCH * MLPD;
    unsigned short* Wm1pk = W2b + (size_t)BOT * PRE;
    unsigned short* Wm2pk = Wm1pk + (size_t)MLPD * AK;
    unsigned short* W1pk  = Wm2pk + (size_t)H * MLPD;   // 512*128 (packed)
    unsigned short* Whpk  = W1pk + (size_t)PRE * H;     // 512*128 (packed)

    float* out  = (float*)d_out;
    float* loss = out + SEQ * BATCH * 2;

    prep_kernel<<<(PREP_TOT + 255) / 256, 256, 0, stream>>>(
        W2, Wm1, Wm2, W1, Wp, bp, b1, ch, hh, last_pos, Wih, Whh, bih, bhh, Wse, bse,
        W2b, Wm1pk, Wm2pk, W1pk, Wcx, Wcy, biash, cbuf, hbuf, pos, Whpk, Wx0, Wx1, bx, loss);

    for (int t = 0; t < SEQ; t++) {
        const float* relin = (t == 0) ? last_pos_rel : (ptr_rel + (t - 1) * BATCH * 2);
        const float* gt = ptr_rel + t * BATCH * 2;
        // fused LSTM gates (MFMA, K=128, packed-B) + Hpart (MFMA, packed-B) + rel_pos/loss
        lstm_hpart<<<BATCH / LROWS, 512, 0, stream>>>(t, relin, gt, Whpk, Wx0, Wx1, bx,
                                                      Wpos, bpos, W1pk, biash, hbuf, cbuf,
                                                      Abf, Hpartf, pos,
                                                      out + t * BATCH * 2, loss);
        if (t == SEQ - 1) break;   // h after last step is dead
        // fused x1-build + pool GEMM + max_j
        pool_fused<<<dim3(2, 128), 512, 0, stream>>>(Hpartf, pos, Wcx, Wcy, W2b, b2, Abf);
        // R7: fused MLP (dh in LDS; was 2 split-K launches + dhbf round-trip)
        mlp_fused<<<BATCH / 16, 512, 0, stream>>>(Abf, Wm1pk, bm1, Wm2pk, bm2, hbuf);
    }
}

// Round 8
// 844.867 us; speedup vs baseline: 1.3228x; 1.3228x over previous
//
#include <hip/hip_runtime.h>
#include <math.h>

#define BATCH 512
#define NG 16
#define GSZ 32
#define H 128
#define E 64
#define PRE 512
#define BOT 1024
#define MLPD 1024
#define SEQ 12
#define AK 1152   // Abf row length = H + BOT

typedef __attribute__((ext_vector_type(8))) short bf16x8;
typedef __attribute__((ext_vector_type(4))) float f32x4;

union bf8pack { ushort s[8]; uint4 v; };

__device__ __forceinline__ unsigned short f2bf(float f) {
    unsigned u = __float_as_uint(f);
    u += 0x7FFF + ((u >> 16) & 1);   // round-to-nearest-even
    return (unsigned short)(u >> 16);
}
__device__ __forceinline__ float bf2f(unsigned short s) {
    return __uint_as_float(((unsigned)s) << 16);
}

#define GLB(p) ((const __attribute__((address_space(1))) unsigned int*)(p))
#define LDS(p) ((__attribute__((address_space(3))) unsigned int*)(p))

// ---------------------------------------------------------------- one-shot prep
#define N0 (BOT * PRE)        /* W2b   */
#define N1 (MLPD * AK)        /* Wm1b  */
#define N2 (H * MLPD)         /* Wm2b  */
#define N3 (PRE * H)          /* W1pk: MFMA-fragment-packed W1[:,64:192] (R4) */
#define N4 (PRE)              /* wc    */
#define N5 (BATCH * H)        /* c     */
#define N5b (BATCH * H)       /* h0 = hh */
#define N6 (BATCH * 2)        /* pos   */
#define N7 (512 * 128)        /* Whpk: MFMA-fragment-packed Whh (R4) */
#define N8 (512)              /* Wx0/Wx1/bx: rank-2 fold of dec_in@Wih^T (R3) */
#define PREP_TOT (N0 + N1 + N2 + N3 + N4 + N5 + N5b + N6 + N7 + N8 + 1)

__global__ void prep_kernel(
    const float* __restrict__ W2, const float* __restrict__ Wm1,
    const float* __restrict__ Wm2, const float* __restrict__ W1,
    const float* __restrict__ Wp, const float* __restrict__ bp, const float* __restrict__ b1,
    const float* __restrict__ ch, const float* __restrict__ hh, const float* __restrict__ last_pos,
    const float* __restrict__ Wih, const float* __restrict__ Whh,
    const float* __restrict__ bih, const float* __restrict__ bhh,
    const float* __restrict__ Wse, const float* __restrict__ bse,
    unsigned short* __restrict__ W2b, unsigned short* __restrict__ Wm1b,
    unsigned short* __restrict__ Wm2b, unsigned short* __restrict__ W1pk,
    float* __restrict__ Wcx, float* __restrict__ Wcy, float* __restrict__ biash,
    float* __restrict__ cbuf, float* __restrict__ hbuf, float* __restrict__ pos,
    unsigned short* __restrict__ Whpk,
    float* __restrict__ Wx0, float* __restrict__ Wx1, float* __restrict__ bx,
    float* __restrict__ loss)
{
    long idx = (long)blockIdx.x * 256 + threadIdx.x;
    if (idx < N0) { W2b[idx] = f2bf(W2[idx]); return; }
    idx -= N0;
    if (idx < N1) { Wm1b[idx] = f2bf(Wm1[idx]); return; }
    idx -= N1;
    if (idx < N2) { Wm2b[idx] = f2bf(Wm2[idx]); return; }
    idx -= N2;
    if (idx < N3) {
        // W1pk[(((w*4+ks)*4+nt)*4+quad)*16 + l16][e] = W1[col*192 + 64 + k]
        int e = (int)(idx & 7);
        int u = (int)(idx >> 3);
        int l16 = u & 15, quad = (u >> 4) & 3, nt = (u >> 6) & 3, ks = (u >> 8) & 3, w = u >> 10;
        int col = w * 64 + nt * 16 + l16;
        int k = ks * 32 + quad * 8 + e;
        W1pk[idx] = f2bf(W1[col * 192 + E + k]);
        return;
    }
    idx -= N3;
    if (idx < N4) {
        int p = (int)idx;
        float sx = 0.f, sy = 0.f, sb = 0.f;
#pragma unroll 8
        for (int e = 0; e < E; ++e) {
            float w = W1[p * 192 + e];
            sx += w * Wp[e * 2 + 0];
            sy += w * Wp[e * 2 + 1];
            sb += w * bp[e];
        }
        Wcx[p] = sx; Wcy[p] = sy; biash[p] = b1[p] + sb;
        return;
    }
    idx -= N4;
    if (idx < N5) { cbuf[idx] = ch[idx]; return; }
    idx -= N5;
    if (idx < N5b) { hbuf[idx] = hh[idx]; return; }
    idx -= N5b;
    if (idx < N6) { pos[idx] = last_pos[idx]; return; }
    idx -= N6;
    if (idx < N7) {
        // Whpk[(((g*8+w)*4+ks)*4+quad)*16 + l16][e] = Whh[col*128 + k]
        int e = (int)(idx & 7);
        int u = (int)(idx >> 3);
        int l16 = u & 15, quad = (u >> 4) & 3, ks = (u >> 6) & 3, w = (u >> 8) & 7, g = u >> 11;
        int col = g * 128 + w * 16 + l16;
        int k = ks * 32 + quad * 8 + e;
        Whpk[idx] = f2bf(Whh[col * H + k]);
        return;
    }
    idx -= N7;
    if (idx < N8) {
        int u = (int)idx;
        float sx = 0.f, sy = 0.f, sb = 0.f;
#pragma unroll 8
        for (int e = 0; e < E; ++e) {
            float w = Wih[u * E + e];
            sx += w * Wse[e * 2 + 0];
            sy += w * Wse[e * 2 + 1];
            sb += w * bse[e];
        }
        Wx0[u] = sx; Wx1[u] = sy; bx[u] = sb + bih[u] + bhh[u];
        return;
    }
    idx -= N8;
    if (idx == 0) *loss = 0.0f;
}

// ---------------------------------------------------------------- fused LSTM + Hpart
// R2: 32 blocks x 512 threads, 16 rows/block, 8 waves.
// R3: dec_in@Wih^T folded to rank-2 -> gate GEMM K=128.
// R4: B-operands pre-packed in MFMA fragment order (base + lane*16B loads).
#define LROWS 16
__global__ __launch_bounds__(512) void lstm_hpart(
    int t,
    const float* __restrict__ relin, const float* __restrict__ gt,
    const unsigned short* __restrict__ Whpk,
    const float* __restrict__ Wx0, const float* __restrict__ Wx1, const float* __restrict__ bx,
    const float* __restrict__ Wpos, const float* __restrict__ bpos,
    const unsigned short* __restrict__ W1pk, const float* __restrict__ biash,
    const float* __restrict__ hbuf, float* __restrict__ cbuf,
    unsigned short* __restrict__ Abf, float* __restrict__ Hpartf,
    float* __restrict__ pos, float* __restrict__ traj, float* __restrict__ loss)
{
    constexpr int LDHB = 136;
    constexpr int LDHF = 129;
    __shared__ __align__(16) unsigned short As[LROWS * LDHB];
    __shared__ __align__(16) unsigned short hnb[LROWS * LDHB];
    __shared__ float hnf[LROWS * LDHF];
    const int r0 = blockIdx.x * LROWS;     // global row base
    const int tid = threadIdx.x;
    const int lane = tid & 63, w = tid >> 6;          // w in 0..7
    const int quad = lane >> 4, l16 = lane & 15;

    // ---- build A = bf16(h_in) : 16 x 128 ----
    for (int idx = tid; idx < LROWS * H; idx += 512) {
        int row = idx >> 7, k = idx & 127;
        As[row * LDHB + k] = f2bf(hbuf[(size_t)(r0 + row) * H + k]);
    }
    __syncthreads();

    // ---- gate GEMM (K=128): wave w -> u-slice [w*16, w*16+16), all 4 gates ----
    f32x4 acc[4];
#pragma unroll
    for (int g4 = 0; g4 < 4; ++g4) acc[g4] = (f32x4)0.f;
#pragma unroll
    for (int ks = 0; ks < 4; ++ks) {
        bf16x8 af = *(const bf16x8*)&As[l16 * LDHB + ks * 32 + quad * 8];
#pragma unroll
        for (int gate = 0; gate < 4; ++gate) {
            bf16x8 bf = *(const bf16x8*)&Whpk[((size_t)((gate * 8 + w) * 4 + ks) * 64 + lane) * 8];
            acc[gate] = __builtin_amdgcn_mfma_f32_16x16x32_bf16(af, bf, acc[gate], 0, 0, 0);
        }
    }

    // ---- nonlinearity + c update (u = w*16 + l16, rows = quad*4+r) ----
    {
        int u = w * 16 + l16;
        float wx0[4], wx1[4], bxv[4];
#pragma unroll
        for (int gate = 0; gate < 4; ++gate) {
            int col = gate * 128 + u;
            wx0[gate] = Wx0[col]; wx1[gate] = Wx1[col]; bxv[gate] = bx[col];
        }
#pragma unroll
        for (int r = 0; r < 4; ++r) {
            int row = quad * 4 + r;
            int b = r0 + row;
            float rx = relin[b * 2 + 0], ry = relin[b * 2 + 1];
            float i_ = acc[0][r] + rx * wx0[0] + ry * wx1[0] + bxv[0];
            float f_ = acc[1][r] + rx * wx0[1] + ry * wx1[1] + bxv[1];
            float g_ = acc[2][r] + rx * wx0[2] + ry * wx1[2] + bxv[2];
            float o_ = acc[3][r] + rx * wx0[3] + ry * wx1[3] + bxv[3];
            float ig = 1.0f / (1.0f + expf(-i_));
            float fg = 1.0f / (1.0f + expf(-f_));
            float gg = tanhf(g_);
            float og = 1.0f / (1.0f + expf(-o_));
            float c = fg * cbuf[(size_t)b * H + u] + ig * gg;
            cbuf[(size_t)b * H + u] = c;
            float h = og * tanhf(c);
            hnb[row * LDHB + u] = f2bf(h);
            hnf[row * LDHF + u] = h;
            Abf[(size_t)b * AK + u] = f2bf(h);
        }
    }
    __syncthreads();

    // ---- Hpart GEMM (dead at last step): wave w -> cols [w*64, w*64+64) ----
    if (t < SEQ - 1) {
        f32x4 acc2[4];
#pragma unroll
        for (int nt = 0; nt < 4; ++nt) acc2[nt] = (f32x4)0.f;
#pragma unroll
        for (int ks = 0; ks < 4; ++ks) {
            bf16x8 af = *(const bf16x8*)&hnb[l16 * LDHB + ks * 32 + quad * 8];
#pragma unroll
            for (int nt = 0; nt < 4; ++nt) {
                bf16x8 bfr = *(const bf16x8*)&W1pk[((size_t)((w * 4 + ks) * 4 + nt) * 64 + lane) * 8];
                acc2[nt] = __builtin_amdgcn_mfma_f32_16x16x32_bf16(af, bfr, acc2[nt], 0, 0, 0);
            }
        }
#pragma unroll
        for (int nt = 0; nt < 4; ++nt) {
            int col = w * 64 + nt * 16 + l16;
            float bv = biash[col];
#pragma unroll
            for (int r = 0; r < 4; ++r) {
                int row = quad * 4 + r;
                Hpartf[(size_t)(r0 + row) * PRE + col] = acc2[nt][r] + bv;
            }
        }
    }

    // ---- rel_pos / curr_pos / traj / loss — 512 threads, 16-seg shfl reduce ----
    {
        int row = tid >> 5, o = (tid >> 4) & 1, seg = tid & 15;
        const float* wr = Wpos + o * H + seg * 8;
        const float* hr = &hnf[row * LDHF + seg * 8];
        float acc3 = 0.f;
#pragma unroll
        for (int k = 0; k < 8; ++k) acc3 += wr[k] * hr[k];
        acc3 += __shfl_xor(acc3, 1);
        acc3 += __shfl_xor(acc3, 2);
        acc3 += __shfl_xor(acc3, 4);
        acc3 += __shfl_xor(acc3, 8);
        if (seg == 0) {
            acc3 += bpos[o];
            int b = r0 + row;
            float lp = pos[b * 2 + o];
            pos[b * 2 + o] = acc3 + lp;
            traj[b * 2 + o] = acc3;
            float d = acc3 - gt[b * 2 + o];
            atomicAdd(loss, d * d * (1.0f / 1024.0f));
        }
    }
}

// ---------------------------------------------------------------- split-K bf16 MFMA GEMM (R3, re-instated R8)
// C = A(MxK) @ B(NxK)^T; 256 thr = 4 waves; wave w: kslice = w/NW, nslice = w%NW.
// MODE 1: Cb = bf16(relu(acc+bias)) | MODE 2: Cf = relu(acc+bias)
template <int BM, int BN, int KW, int NW, int MODE>
__global__ __launch_bounds__(256) void gemm_splitk(
    const unsigned short* __restrict__ A, int lda,
    const unsigned short* __restrict__ B, int ldb, int K,
    const float* __restrict__ bias,
    float* __restrict__ Cf, unsigned short* __restrict__ Cb, int ldc)
{
    constexpr int MT = BM / 16;            // A frags per wave
    constexpr int NT = BN / (16 * NW);     // B frags per wave
    __shared__ __align__(16) unsigned short As[KW * BM * 64];
    __shared__ __align__(16) unsigned short Bs[KW * BN * 64];
    __shared__ float red[KW * BM * BN];
    int tid = threadIdx.x;
    int lane = tid & 63, w = tid >> 6;
    int kslice = w / NW, nslice = w % NW;
    int gtid = tid & (NW * 64 - 1);
    int quad = lane >> 4, l16 = lane & 15;
    int m0 = blockIdx.y * BM, n0 = blockIdx.x * BN;
    const int KC = K / KW;                 // K per slice (multiple of 64)

    f32x4 acc[MT][NT];
#pragma unroll
    for (int mt = 0; mt < MT; ++mt)
#pragma unroll
        for (int nt = 0; nt < NT; ++nt) acc[mt][nt] = (f32x4)0.f;

    for (int k0 = 0; k0 < KC; k0 += 64) {
        int kb = kslice * KC + k0;
#pragma unroll
        for (int u = 0; u < BM / (8 * NW); ++u) {
            int c = u * NW * 64 + gtid;
            __builtin_amdgcn_global_load_lds(
                GLB(A + (size_t)(m0 + (c >> 3)) * lda + kb + (c & 7) * 8),
                LDS(&As[kslice * BM * 64 + c * 8]), 16, 0, 0);
        }
#pragma unroll
        for (int u = 0; u < BN / (8 * NW); ++u) {
            int c = u * NW * 64 + gtid;
            __builtin_amdgcn_global_load_lds(
                GLB(B + (size_t)(n0 + (c >> 3)) * ldb + kb + (c & 7) * 8),
                LDS(&Bs[kslice * BN * 64 + c * 8]), 16, 0, 0);
        }
        __syncthreads();
#pragma unroll
        for (int ks = 0; ks < 2; ++ks) {
            bf16x8 af[MT], bfr[NT];
#pragma unroll
            for (int mt = 0; mt < MT; ++mt)
                af[mt] = *(const bf16x8*)&As[kslice * BM * 64 + (mt * 16 + l16) * 64 + ks * 32 + quad * 8];
#pragma unroll
            for (int nt = 0; nt < NT; ++nt)
                bfr[nt] = *(const bf16x8*)&Bs[kslice * BN * 64 + (nslice * (BN / NW) + nt * 16 + l16) * 64 + ks * 32 + quad * 8];
#pragma unroll
            for (int mt = 0; mt < MT; ++mt)
#pragma unroll
                for (int nt = 0; nt < NT; ++nt)
                    acc[mt][nt] = __builtin_amdgcn_mfma_f32_16x16x32_bf16(af[mt], bfr[nt], acc[mt][nt], 0, 0, 0);
        }
        __syncthreads();
    }

    // ---- partials -> LDS ----
#pragma unroll
    for (int mt = 0; mt < MT; ++mt)
#pragma unroll
    for (int nt = 0; nt < NT; ++nt) {
#pragma unroll
        for (int r = 0; r < 4; ++r) {
            int row = mt * 16 + quad * 4 + r;
            int col = nslice * (BN / NW) + nt * 16 + l16;
            red[kslice * BM * BN + row * BN + col] = acc[mt][nt][r];
        }
    }
    __syncthreads();

    // ---- reduce KW partials + bias + relu + store ----
#pragma unroll
    for (int o = 0; o < BM * BN / 256; ++o) {
        int e = o * 256 + tid;
        int row = e / BN, col = e % BN;
        float s = 0.f;
#pragma unroll
        for (int k = 0; k < KW; ++k) s += red[k * BM * BN + e];
        float v = fmaxf(s + bias[n0 + col], 0.f);
        if (MODE == 1) Cb[(size_t)(m0 + row) * ldc + n0 + col] = f2bf(v);
        else           Cf[(size_t)(m0 + row) * ldc + n0 + col] = v;
    }
}

// ---------------------------------------------------------------- fused x1-build + pool GEMM + max_j
// R5/R6: A-tile built in LDS from Hpart/pos/Wc* each K-step.
// R8: BN 512 -> 256 (grid 4x128 = 512 blocks, ~50KB LDS -> 2-3 blocks/CU co-resident:
// one block's MFMA hides the other's staging drain; shorter 32-MFMA chain per K-step).
__global__ __launch_bounds__(512) void pool_fused(
    const float* __restrict__ Hpartf, const float* __restrict__ pos,
    const float* __restrict__ Wcx, const float* __restrict__ Wcy,
    const unsigned short* __restrict__ W2b,
    const float* __restrict__ b2, unsigned short* __restrict__ Abf)
{
    constexpr int BN = 256;
    constexpr int LDA = 72;    // pad: row stride 144B -> 4-bank offset/row, 2-way (free)
    __shared__ __align__(16) unsigned short As[128 * LDA];   // 18 KB
    __shared__ __align__(16) unsigned short Bs[BN * 64];     // 32 KB
    const int tid = threadIdx.x;
    const int lane = tid & 63, w = tid >> 6;       // 8 waves
    const int quad = lane >> 4, l16 = lane & 15;
    const int n_tile = blockIdx.x, m_tile = blockIdx.y;
    const int g = m_tile >> 3, iq = m_tile & 7;
    const int n0 = n_tile * BN;

    // per-thread build coords (loop-invariant): thread -> (row, 16-col slab)
    const int brow = tid >> 2;                 // 0..127
    const int k8 = (tid & 3) * 16;             // col base within K-step
    const int bi = iq * 4 + (brow >> 5), bj = brow & 31;
    const float rx = pos[(g * GSZ + bj) * 2 + 0] - pos[(g * GSZ + bi) * 2 + 0];
    const float ry = pos[(g * GSZ + bj) * 2 + 1] - pos[(g * GSZ + bi) * 2 + 1];
    const float* hrow = &Hpartf[(size_t)(g * GSZ + bj) * PRE];

    f32x4 acc[8][2];
#pragma unroll
    for (int mt = 0; mt < 8; ++mt)
#pragma unroll
        for (int nt = 0; nt < 2; ++nt) acc[mt][nt] = (f32x4)0.f;

    for (int k0 = 0; k0 < PRE; k0 += 64) {
        // stage B: 256 rows x 64 cols bf16 = 32KB, 4 x global_load_lds/thread
#pragma unroll
        for (int it = 0; it < 4; ++it) {
            int c = it * 512 + tid;
            __builtin_amdgcn_global_load_lds(
                GLB(W2b + (size_t)(n0 + (c >> 3)) * PRE + k0 + (c & 7) * 8),
                LDS(&Bs[c * 8]), 16, 0, 0);
        }
        // build A: As[row][kk] = bf16(relu(Hpart[j][k0+kk] + rx*Wcx + ry*Wcy))
        {
            const float4* hp = (const float4*)(hrow + k0 + k8);
            const float4* wx = (const float4*)(Wcx + k0 + k8);
            const float4* wy = (const float4*)(Wcy + k0 + k8);
            bf8pack o[2];
#pragma unroll
            for (int q = 0; q < 2; ++q) {
                float4 ha = hp[q * 2], hb = hp[q * 2 + 1];
                float4 xa = wx[q * 2], xb = wx[q * 2 + 1];
                float4 ya = wy[q * 2], yb = wy[q * 2 + 1];
                o[q].s[0] = f2bf(fmaxf(ha.x + rx * xa.x + ry * ya.x, 0.f));
                o[q].s[1] = f2bf(fmaxf(ha.y + rx * xa.y + ry * ya.y, 0.f));
                o[q].s[2] = f2bf(fmaxf(ha.z + rx * xa.z + ry * ya.z, 0.f));
                o[q].s[3] = f2bf(fmaxf(ha.w + rx * xa.w + ry * ya.w, 0.f));
                o[q].s[4] = f2bf(fmaxf(hb.x + rx * xb.x + ry * yb.x, 0.f));
                o[q].s[5] = f2bf(fmaxf(hb.y + rx * xb.y + ry * yb.y, 0.f));
                o[q].s[6] = f2bf(fmaxf(hb.z + rx * xb.z + ry * yb.z, 0.f));
                o[q].s[7] = f2bf(fmaxf(hb.w + rx * xb.w + ry * yb.w, 0.f));
            }
            *(uint4*)&As[brow * LDA + k8] = o[0].v;
            *(uint4*)&As[brow * LDA + k8 + 8] = o[1].v;
        }
        __syncthreads();
#pragma unroll
        for (int ks = 0; ks < 2; ++ks) {
            bf16x8 bfr[2];
#pragma unroll
            for (int nt = 0; nt < 2; ++nt)
                bfr[nt] = *(const bf16x8*)&Bs[(w * 32 + nt * 16 + l16) * 64 + ks * 32 + quad * 8];
#pragma unroll
            for (int mt = 0; mt < 8; ++mt) {
                bf16x8 af = *(const bf16x8*)&As[(mt * 16 + l16) * LDA + ks * 32 + quad * 8];
#pragma unroll
                for (int nt = 0; nt < 2; ++nt)
                    acc[mt][nt] = __builtin_amdgcn_mfma_f32_16x16x32_bf16(af, bfr[nt], acc[mt][nt], 0, 0, 0);
            }
        }
        __syncthreads();
    }

    // ---- max over j: rows il*32..il*32+31 live in acc[2il..2il+1] x quad lanes ----
#pragma unroll
    for (int il = 0; il < 4; ++il)
#pragma unroll
    for (int nt = 0; nt < 2; ++nt) {
        float u = -1e30f;
#pragma unroll
        for (int p = 0; p < 2; ++p)
#pragma unroll
            for (int r = 0; r < 4; ++r) u = fmaxf(u, acc[il * 2 + p][nt][r]);
        u = fmaxf(u, __shfl_xor(u, 16));
        u = fmaxf(u, __shfl_xor(u, 32));
        if (lane < 16) {
            int col = n0 + w * 32 + nt * 16 + l16;
            int gu = m_tile * 4 + il;
            Abf[(size_t)gu * AK + H + col] = f2bf(fmaxf(u + b2[col], 0.f));
        }
    }
}

// ---------------------------------------------------------------- launch
extern "C" void kernel_launch(void* const* d_in, const int* in_sizes, int n_in,
                              void* d_out, int out_size, void* d_ws, size_t ws_size,
                              hipStream_t stream)
{
    const float* last_pos     = (const float*)d_in[0];
    const float* last_pos_rel = (const float*)d_in[1];
    const float* hh           = (const float*)d_in[2];
    const float* ch           = (const float*)d_in[3];
    const float* ptr_rel      = (const float*)d_in[4];
    const float* Wih  = (const float*)d_in[6];
    const float* Whh  = (const float*)d_in[7];
    const float* bih  = (const float*)d_in[8];
    const float* bhh  = (const float*)d_in[9];
    const float* Wse  = (const float*)d_in[10];
    const float* bse  = (const float*)d_in[11];
    const float* Wpos = (const float*)d_in[12];
    const float* bpos = (const float*)d_in[13];
    const float* Wp   = (const float*)d_in[14];
    const float* bp   = (const float*)d_in[15];
    const float* W1   = (const float*)d_in[16];
    const float* b1   = (const float*)d_in[17];
    const float* W2   = (const float*)d_in[18];
    const float* b2   = (const float*)d_in[19];
    const float* Wm1  = (const float*)d_in[20];
    const float* bm1  = (const float*)d_in[21];
    const float* Wm2  = (const float*)d_in[22];
    const float* bm2  = (const float*)d_in[23];

    float* ws     = (float*)d_ws;
    float* hbuf   = ws;                       // 65536
    float* cbuf   = hbuf + BATCH * H;         // 65536
    float* pos    = cbuf + BATCH * H;         // 1024 (padded)
    float* Hpartf = pos + 1024;               // 262144
    float* Wcx    = Hpartf + BATCH * PRE;     // 512
    float* Wcy    = Wcx + PRE;                // 512
    float* biash  = Wcy + PRE;                // 512
    float* bx     = biash + PRE;              // 512
    float* Wx0    = bx + 512;                 // 512
    float* Wx1    = Wx0 + 512;                // 512
    unsigned short* ub    = (unsigned short*)(Wx1 + 512);
    unsigned short* Abf   = ub;                         // 512*1152
    unsigned short* dhbf  = Abf + (size_t)BATCH * AK;   // 512*1024
    unsigned short* W2b   = dhbf + (size_t)BATCH * MLPD;
    unsigned short* Wm1b  = W2b + (size_t)BOT * PRE;
    unsigned short* Wm2b  = Wm1b + (size_t)MLPD * AK;
    unsigned short* W1pk  = Wm2b + (size_t)H * MLPD;    // 512*128 (packed)
    unsigned short* Whpk  = W1pk + (size_t)PRE * H;     // 512*128 (packed)

    float* out  = (float*)d_out;
    float* loss = out + SEQ * BATCH * 2;

    prep_kernel<<<(PREP_TOT + 255) / 256, 256, 0, stream>>>(
        W2, Wm1, Wm2, W1, Wp, bp, b1, ch, hh, last_pos, Wih, Whh, bih, bhh, Wse, bse,
        W2b, Wm1b, Wm2b, W1pk, Wcx, Wcy, biash, cbuf, hbuf, pos, Whpk, Wx0, Wx1, bx, loss);

    for (int t = 0; t < SEQ; t++) {
        const float* relin = (t == 0) ? last_pos_rel : (ptr_rel + (t - 1) * BATCH * 2);
        const float* gt = ptr_rel + t * BATCH * 2;
        // fused LSTM gates (MFMA, K=128, packed-B) + Hpart (MFMA, packed-B) + rel_pos/loss
        lstm_hpart<<<BATCH / LROWS, 512, 0, stream>>>(t, relin, gt, Whpk, Wx0, Wx1, bx,
                                                      Wpos, bpos, W1pk, biash, hbuf, cbuf,
                                                      Abf, Hpartf, pos,
                                                      out + t * BATCH * 2, loss);
        if (t == SEQ - 1) break;   // h after last step is dead
        // fused x1-build + pool GEMM + max_j — R8: BN=256, 512 blocks, 2-3 blocks/CU
        pool_fused<<<dim3(4, 128), 512, 0, stream>>>(Hpartf, pos, Wcx, Wcy, W2b, b2, Abf);
        // dh = bf16(relu([h|pool] @ Wm1^T + bm1)) — 2-way split-K (R6-proven, re-instated)
        gemm_splitk<64, 32, 2, 2, 1><<<dim3(MLPD / 32, BATCH / 64), 256, 0, stream>>>(
            Abf, AK, Wm1b, AK, AK, bm1, nullptr, dhbf, MLPD);
        // h = relu(dh @ Wm2^T + bm2) -> fp32 hbuf — 4-way split-K, BM=16 (R6-proven)
        gemm_splitk<16, 32, 4, 1, 2><<<dim3(H / 32, BATCH / 16), 256, 0, stream>>>(
            dhbf, MLPD, Wm2b, MLPD, MLPD, bm2, hbuf, nullptr, H);
    }
}

// Round 9
// 730.810 us; speedup vs baseline: 1.5292x; 1.1561x over previous
//
#include <hip/hip_runtime.h>
#include <math.h>

#define BATCH 512
#define NG 16
#define GSZ 32
#define H 128
#define E 64
#define PRE 512
#define BOT 1024
#define MLPD 1024
#define SEQ 12
#define AK 1152   // Abf row length = H + BOT

typedef __attribute__((ext_vector_type(8))) short bf16x8;
typedef __attribute__((ext_vector_type(4))) float f32x4;

union bf8pack { ushort s[8]; uint4 v; };

__device__ __forceinline__ unsigned short f2bf(float f) {
    unsigned u = __float_as_uint(f);
    u += 0x7FFF + ((u >> 16) & 1);   // round-to-nearest-even
    return (unsigned short)(u >> 16);
}
__device__ __forceinline__ float bf2f(unsigned short s) {
    return __uint_as_float(((unsigned)s) << 16);
}

#define GLB(p) ((const __attribute__((address_space(1))) unsigned int*)(p))
#define LDS(p) ((__attribute__((address_space(3))) unsigned int*)(p))

// ---------------------------------------------------------------- one-shot prep
#define N0 (BOT * PRE)        /* W2pk: MFMA-fragment-packed W2 (R9) */
#define N1 (MLPD * AK)        /* Wm1b  */
#define N2 (H * MLPD)         /* Wm2b  */
#define N3 (PRE * H)          /* W1pk: MFMA-fragment-packed W1[:,64:192] (R4) */
#define N4 (PRE)              /* wc    */
#define N5 (BATCH * H)        /* c     */
#define N5b (BATCH * H)       /* h0 = hh */
#define N6 (BATCH * 2)        /* pos   */
#define N7 (512 * 128)        /* Whpk: MFMA-fragment-packed Whh (R4) */
#define N8 (512)              /* Wx0/Wx1/bx: rank-2 fold of dec_in@Wih^T (R3) */
#define PREP_TOT (N0 + N1 + N2 + N3 + N4 + N5 + N5b + N6 + N7 + N8 + 1)

__global__ void prep_kernel(
    const float* __restrict__ W2, const float* __restrict__ Wm1,
    const float* __restrict__ Wm2, const float* __restrict__ W1,
    const float* __restrict__ Wp, const float* __restrict__ bp, const float* __restrict__ b1,
    const float* __restrict__ ch, const float* __restrict__ hh, const float* __restrict__ last_pos,
    const float* __restrict__ Wih, const float* __restrict__ Whh,
    const float* __restrict__ bih, const float* __restrict__ bhh,
    const float* __restrict__ Wse, const float* __restrict__ bse,
    unsigned short* __restrict__ W2pk, unsigned short* __restrict__ Wm1b,
    unsigned short* __restrict__ Wm2b, unsigned short* __restrict__ W1pk,
    float* __restrict__ Wcx, float* __restrict__ Wcy, float* __restrict__ biash,
    float* __restrict__ cbuf, float* __restrict__ hbuf, float* __restrict__ pos,
    unsigned short* __restrict__ Whpk,
    float* __restrict__ Wx0, float* __restrict__ Wx1, float* __restrict__ bx,
    float* __restrict__ loss)
{
    long idx = (long)blockIdx.x * 256 + threadIdx.x;
    if (idx < N0) {
        // W2pk[((cg*16+ksg)*64 + lane)*8 + e] = W2[col*512 + kk]
        //   col = cg*16 + (lane&15), kk = ksg*32 + (lane>>4)*8 + e
        // -> pool_fused B-fragment load is base + lane*16B (coalesced, no LDS staging)
        int e = (int)(idx & 7);
        long u = idx >> 3;
        int lane = (int)(u & 63);
        int rest = (int)(u >> 6);            // 0 .. 1023
        int ksg = rest & 15, cg = rest >> 4; // cg 0..63
        int col = cg * 16 + (lane & 15);
        int kk = ksg * 32 + (lane >> 4) * 8 + e;
        W2pk[idx] = f2bf(W2[(size_t)col * PRE + kk]);
        return;
    }
    idx -= N0;
    if (idx < N1) { Wm1b[idx] = f2bf(Wm1[idx]); return; }
    idx -= N1;
    if (idx < N2) { Wm2b[idx] = f2bf(Wm2[idx]); return; }
    idx -= N2;
    if (idx < N3) {
        // W1pk[(((w*4+ks)*4+nt)*4+quad)*16 + l16][e] = W1[col*192 + 64 + k]
        int e = (int)(idx & 7);
        int u = (int)(idx >> 3);
        int l16 = u & 15, quad = (u >> 4) & 3, nt = (u >> 6) & 3, ks = (u >> 8) & 3, w = u >> 10;
        int col = w * 64 + nt * 16 + l16;
        int k = ks * 32 + quad * 8 + e;
        W1pk[idx] = f2bf(W1[col * 192 + E + k]);
        return;
    }
    idx -= N3;
    if (idx < N4) {
        int p = (int)idx;
        float sx = 0.f, sy = 0.f, sb = 0.f;
#pragma unroll 8
        for (int e = 0; e < E; ++e) {
            float w = W1[p * 192 + e];
            sx += w * Wp[e * 2 + 0];
            sy += w * Wp[e * 2 + 1];
            sb += w * bp[e];
        }
        Wcx[p] = sx; Wcy[p] = sy; biash[p] = b1[p] + sb;
        return;
    }
    idx -= N4;
    if (idx < N5) { cbuf[idx] = ch[idx]; return; }
    idx -= N5;
    if (idx < N5b) { hbuf[idx] = hh[idx]; return; }
    idx -= N5b;
    if (idx < N6) { pos[idx] = last_pos[idx]; return; }
    idx -= N6;
    if (idx < N7) {
        // Whpk[(((g*8+w)*4+ks)*4+quad)*16 + l16][e] = Whh[col*128 + k]
        int e = (int)(idx & 7);
        int u = (int)(idx >> 3);
        int l16 = u & 15, quad = (u >> 4) & 3, ks = (u >> 6) & 3, w = (u >> 8) & 7, g = u >> 11;
        int col = g * 128 + w * 16 + l16;
        int k = ks * 32 + quad * 8 + e;
        Whpk[idx] = f2bf(Whh[col * H + k]);
        return;
    }
    idx -= N7;
    if (idx < N8) {
        int u = (int)idx;
        float sx = 0.f, sy = 0.f, sb = 0.f;
#pragma unroll 8
        for (int e = 0; e < E; ++e) {
            float w = Wih[u * E + e];
            sx += w * Wse[e * 2 + 0];
            sy += w * Wse[e * 2 + 1];
            sb += w * bse[e];
        }
        Wx0[u] = sx; Wx1[u] = sy; bx[u] = sb + bih[u] + bhh[u];
        return;
    }
    idx -= N8;
    if (idx == 0) *loss = 0.0f;
}

// ---------------------------------------------------------------- fused LSTM + Hpart
// R2: 32 blocks x 512 threads, 16 rows/block, 8 waves.
// R3: dec_in@Wih^T folded to rank-2 -> gate GEMM K=128.
// R4: B-operands pre-packed in MFMA fragment order (base + lane*16B loads).
#define LROWS 16
__global__ __launch_bounds__(512) void lstm_hpart(
    int t,
    const float* __restrict__ relin, const float* __restrict__ gt,
    const unsigned short* __restrict__ Whpk,
    const float* __restrict__ Wx0, const float* __restrict__ Wx1, const float* __restrict__ bx,
    const float* __restrict__ Wpos, const float* __restrict__ bpos,
    const unsigned short* __restrict__ W1pk, const float* __restrict__ biash,
    const float* __restrict__ hbuf, float* __restrict__ cbuf,
    unsigned short* __restrict__ Abf, float* __restrict__ Hpartf,
    float* __restrict__ pos, float* __restrict__ traj, float* __restrict__ loss)
{
    constexpr int LDHB = 136;
    constexpr int LDHF = 129;
    __shared__ __align__(16) unsigned short As[LROWS * LDHB];
    __shared__ __align__(16) unsigned short hnb[LROWS * LDHB];
    __shared__ float hnf[LROWS * LDHF];
    const int r0 = blockIdx.x * LROWS;     // global row base
    const int tid = threadIdx.x;
    const int lane = tid & 63, w = tid >> 6;          // w in 0..7
    const int quad = lane >> 4, l16 = lane & 15;

    // ---- build A = bf16(h_in) : 16 x 128 ----
    for (int idx = tid; idx < LROWS * H; idx += 512) {
        int row = idx >> 7, k = idx & 127;
        As[row * LDHB + k] = f2bf(hbuf[(size_t)(r0 + row) * H + k]);
    }
    __syncthreads();

    // ---- gate GEMM (K=128): wave w -> u-slice [w*16, w*16+16), all 4 gates ----
    f32x4 acc[4];
#pragma unroll
    for (int g4 = 0; g4 < 4; ++g4) acc[g4] = (f32x4)0.f;
#pragma unroll
    for (int ks = 0; ks < 4; ++ks) {
        bf16x8 af = *(const bf16x8*)&As[l16 * LDHB + ks * 32 + quad * 8];
#pragma unroll
        for (int gate = 0; gate < 4; ++gate) {
            bf16x8 bf = *(const bf16x8*)&Whpk[((size_t)((gate * 8 + w) * 4 + ks) * 64 + lane) * 8];
            acc[gate] = __builtin_amdgcn_mfma_f32_16x16x32_bf16(af, bf, acc[gate], 0, 0, 0);
        }
    }

    // ---- nonlinearity + c update (u = w*16 + l16, rows = quad*4+r) ----
    {
        int u = w * 16 + l16;
        float wx0[4], wx1[4], bxv[4];
#pragma unroll
        for (int gate = 0; gate < 4; ++gate) {
            int col = gate * 128 + u;
            wx0[gate] = Wx0[col]; wx1[gate] = Wx1[col]; bxv[gate] = bx[col];
        }
#pragma unroll
        for (int r = 0; r < 4; ++r) {
            int row = quad * 4 + r;
            int b = r0 + row;
            float rx = relin[b * 2 + 0], ry = relin[b * 2 + 1];
            float i_ = acc[0][r] + rx * wx0[0] + ry * wx1[0] + bxv[0];
            float f_ = acc[1][r] + rx * wx0[1] + ry * wx1[1] + bxv[1];
            float g_ = acc[2][r] + rx * wx0[2] + ry * wx1[2] + bxv[2];
            float o_ = acc[3][r] + rx * wx0[3] + ry * wx1[3] + bxv[3];
            float ig = 1.0f / (1.0f + expf(-i_));
            float fg = 1.0f / (1.0f + expf(-f_));
            float gg = tanhf(g_);
            float og = 1.0f / (1.0f + expf(-o_));
            float c = fg * cbuf[(size_t)b * H + u] + ig * gg;
            cbuf[(size_t)b * H + u] = c;
            float h = og * tanhf(c);
            hnb[row * LDHB + u] = f2bf(h);
            hnf[row * LDHF + u] = h;
            Abf[(size_t)b * AK + u] = f2bf(h);
        }
    }
    __syncthreads();

    // ---- Hpart GEMM (dead at last step): wave w -> cols [w*64, w*64+64) ----
    if (t < SEQ - 1) {
        f32x4 acc2[4];
#pragma unroll
        for (int nt = 0; nt < 4; ++nt) acc2[nt] = (f32x4)0.f;
#pragma unroll
        for (int ks = 0; ks < 4; ++ks) {
            bf16x8 af = *(const bf16x8*)&hnb[l16 * LDHB + ks * 32 + quad * 8];
#pragma unroll
            for (int nt = 0; nt < 4; ++nt) {
                bf16x8 bfr = *(const bf16x8*)&W1pk[((size_t)((w * 4 + ks) * 4 + nt) * 64 + lane) * 8];
                acc2[nt] = __builtin_amdgcn_mfma_f32_16x16x32_bf16(af, bfr, acc2[nt], 0, 0, 0);
            }
        }
#pragma unroll
        for (int nt = 0; nt < 4; ++nt) {
            int col = w * 64 + nt * 16 + l16;
            float bv = biash[col];
#pragma unroll
            for (int r = 0; r < 4; ++r) {
                int row = quad * 4 + r;
                Hpartf[(size_t)(r0 + row) * PRE + col] = acc2[nt][r] + bv;
            }
        }
    }

    // ---- rel_pos / curr_pos / traj / loss — 512 threads, 16-seg shfl reduce ----
    {
        int row = tid >> 5, o = (tid >> 4) & 1, seg = tid & 15;
        const float* wr = Wpos + o * H + seg * 8;
        const float* hr = &hnf[row * LDHF + seg * 8];
        float acc3 = 0.f;
#pragma unroll
        for (int k = 0; k < 8; ++k) acc3 += wr[k] * hr[k];
        acc3 += __shfl_xor(acc3, 1);
        acc3 += __shfl_xor(acc3, 2);
        acc3 += __shfl_xor(acc3, 4);
        acc3 += __shfl_xor(acc3, 8);
        if (seg == 0) {
            acc3 += bpos[o];
            int b = r0 + row;
            float lp = pos[b * 2 + o];
            pos[b * 2 + o] = acc3 + lp;
            traj[b * 2 + o] = acc3;
            float d = acc3 - gt[b * 2 + o];
            atomicAdd(loss, d * d * (1.0f / 1024.0f));
        }
    }
}

// ---------------------------------------------------------------- split-K bf16 MFMA GEMM (R3)
// C = A(MxK) @ B(NxK)^T; 256 thr = 4 waves; wave w: kslice = w/NW, nslice = w%NW.
// MODE 1: Cb = bf16(relu(acc+bias)) | MODE 2: Cf = relu(acc+bias)
template <int BM, int BN, int KW, int NW, int MODE>
__global__ __launch_bounds__(256) void gemm_splitk(
    const unsigned short* __restrict__ A, int lda,
    const unsigned short* __restrict__ B, int ldb, int K,
    const float* __restrict__ bias,
    float* __restrict__ Cf, unsigned short* __restrict__ Cb, int ldc)
{
    constexpr int MT = BM / 16;            // A frags per wave
    constexpr int NT = BN / (16 * NW);     // B frags per wave
    __shared__ __align__(16) unsigned short As[KW * BM * 64];
    __shared__ __align__(16) unsigned short Bs[KW * BN * 64];
    __shared__ float red[KW * BM * BN];
    int tid = threadIdx.x;
    int lane = tid & 63, w = tid >> 6;
    int kslice = w / NW, nslice = w % NW;
    int gtid = tid & (NW * 64 - 1);
    int quad = lane >> 4, l16 = lane & 15;
    int m0 = blockIdx.y * BM, n0 = blockIdx.x * BN;
    const int KC = K / KW;                 // K per slice (multiple of 64)

    f32x4 acc[MT][NT];
#pragma unroll
    for (int mt = 0; mt < MT; ++mt)
#pragma unroll
        for (int nt = 0; nt < NT; ++nt) acc[mt][nt] = (f32x4)0.f;

    for (int k0 = 0; k0 < KC; k0 += 64) {
        int kb = kslice * KC + k0;
#pragma unroll
        for (int u = 0; u < BM / (8 * NW); ++u) {
            int c = u * NW * 64 + gtid;
            __builtin_amdgcn_global_load_lds(
                GLB(A + (size_t)(m0 + (c >> 3)) * lda + kb + (c & 7) * 8),
                LDS(&As[kslice * BM * 64 + c * 8]), 16, 0, 0);
        }
#pragma unroll
        for (int u = 0; u < BN / (8 * NW); ++u) {
            int c = u * NW * 64 + gtid;
            __builtin_amdgcn_global_load_lds(
                GLB(B + (size_t)(n0 + (c >> 3)) * ldb + kb + (c & 7) * 8),
                LDS(&Bs[kslice * BN * 64 + c * 8]), 16, 0, 0);
        }
        __syncthreads();
#pragma unroll
        for (int ks = 0; ks < 2; ++ks) {
            bf16x8 af[MT], bfr[NT];
#pragma unroll
            for (int mt = 0; mt < MT; ++mt)
                af[mt] = *(const bf16x8*)&As[kslice * BM * 64 + (mt * 16 + l16) * 64 + ks * 32 + quad * 8];
#pragma unroll
            for (int nt = 0; nt < NT; ++nt)
                bfr[nt] = *(const bf16x8*)&Bs[kslice * BN * 64 + (nslice * (BN / NW) + nt * 16 + l16) * 64 + ks * 32 + quad * 8];
#pragma unroll
            for (int mt = 0; mt < MT; ++mt)
#pragma unroll
                for (int nt = 0; nt < NT; ++nt)
                    acc[mt][nt] = __builtin_amdgcn_mfma_f32_16x16x32_bf16(af[mt], bfr[nt], acc[mt][nt], 0, 0, 0);
        }
        __syncthreads();
    }

    // ---- partials -> LDS ----
#pragma unroll
    for (int mt = 0; mt < MT; ++mt)
#pragma unroll
    for (int nt = 0; nt < NT; ++nt) {
#pragma unroll
        for (int r = 0; r < 4; ++r) {
            int row = mt * 16 + quad * 4 + r;
            int col = nslice * (BN / NW) + nt * 16 + l16;
            red[kslice * BM * BN + row * BN + col] = acc[mt][nt][r];
        }
    }
    __syncthreads();

    // ---- reduce KW partials + bias + relu + store ----
#pragma unroll
    for (int o = 0; o < BM * BN / 256; ++o) {
        int e = o * 256 + tid;
        int row = e / BN, col = e % BN;
        float s = 0.f;
#pragma unroll
        for (int k = 0; k < KW; ++k) s += red[k * BM * BN + e];
        float v = fmaxf(s + bias[n0 + col], 0.f);
        if (MODE == 1) Cb[(size_t)(m0 + row) * ldc + n0 + col] = f2bf(v);
        else           Cf[(size_t)(m0 + row) * ldc + n0 + col] = v;
    }
}

// ---------------------------------------------------------------- fused x1-build + pool GEMM + max_j
// R5/R6: A-tile built in LDS from Hpart/pos/Wc* each K-step, BN=512.
// R9: B read directly from fragment-packed W2pk (no Bs LDS, no 16-way bank conflict
// that R8 counters exposed: 3.67M SQ_LDS_BANK_CONFLICT). LDS = As only (18KB).
__global__ __launch_bounds__(512) void pool_fused(
    const float* __restrict__ Hpartf, const float* __restrict__ pos,
    const float* __restrict__ Wcx, const float* __restrict__ Wcy,
    const unsigned short* __restrict__ W2pk,
    const float* __restrict__ b2, unsigned short* __restrict__ Abf)
{
    constexpr int BN = 512;
    constexpr int LDA = 72;    // pad: row stride 144B -> 2-way bank aliasing (free, m136)
    __shared__ __align__(16) unsigned short As[128 * LDA];   // 18 KB
    const int tid = threadIdx.x;
    const int lane = tid & 63, w = tid >> 6;       // 8 waves
    const int quad = lane >> 4, l16 = lane & 15;
    const int n_tile = blockIdx.x, m_tile = blockIdx.y;
    const int g = m_tile >> 3, iq = m_tile & 7;
    const int n0 = n_tile * BN;

    // per-thread build coords (loop-invariant): thread -> (row, 16-col slab)
    const int brow = tid >> 2;                 // 0..127
    const int k8 = (tid & 3) * 16;             // col base within K-step
    const int bi = iq * 4 + (brow >> 5), bj = brow & 31;
    const float rx = pos[(g * GSZ + bj) * 2 + 0] - pos[(g * GSZ + bi) * 2 + 0];
    const float ry = pos[(g * GSZ + bj) * 2 + 1] - pos[(g * GSZ + bi) * 2 + 1];
    const float* hrow = &Hpartf[(size_t)(g * GSZ + bj) * PRE];

    f32x4 acc[8][4];
#pragma unroll
    for (int mt = 0; mt < 8; ++mt)
#pragma unroll
        for (int nt = 0; nt < 4; ++nt) acc[mt][nt] = (f32x4)0.f;

    for (int k0i = 0; k0i < 8; ++k0i) {
        const int k0 = k0i * 64;
        // build A: As[row][kk] = bf16(relu(Hpart[j][k0+kk] + rx*Wcx + ry*Wcy))
        {
            const float4* hp = (const float4*)(hrow + k0 + k8);
            const float4* wx = (const float4*)(Wcx + k0 + k8);
            const float4* wy = (const float4*)(Wcy + k0 + k8);
            bf8pack o[2];
#pragma unroll
            for (int q = 0; q < 2; ++q) {
                float4 ha = hp[q * 2], hb = hp[q * 2 + 1];
                float4 xa = wx[q * 2], xb = wx[q * 2 + 1];
                float4 ya = wy[q * 2], yb = wy[q * 2 + 1];
                o[q].s[0] = f2bf(fmaxf(ha.x + rx * xa.x + ry * ya.x, 0.f));
                o[q].s[1] = f2bf(fmaxf(ha.y + rx * xa.y + ry * ya.y, 0.f));
                o[q].s[2] = f2bf(fmaxf(ha.z + rx * xa.z + ry * ya.z, 0.f));
                o[q].s[3] = f2bf(fmaxf(ha.w + rx * xa.w + ry * ya.w, 0.f));
                o[q].s[4] = f2bf(fmaxf(hb.x + rx * xb.x + ry * yb.x, 0.f));
                o[q].s[5] = f2bf(fmaxf(hb.y + rx * xb.y + ry * yb.y, 0.f));
                o[q].s[6] = f2bf(fmaxf(hb.z + rx * xb.z + ry * yb.z, 0.f));
                o[q].s[7] = f2bf(fmaxf(hb.w + rx * xb.w + ry * yb.w, 0.f));
            }
            *(uint4*)&As[brow * LDA + k8] = o[0].v;
            *(uint4*)&As[brow * LDA + k8 + 8] = o[1].v;
        }
        __syncthreads();
#pragma unroll
        for (int ks = 0; ks < 2; ++ks) {
            // B fragments direct from packed global: cg = n0/16 + w*4 + nt, ksg = k0/32 + ks
            bf16x8 bfr[4];
#pragma unroll
            for (int nt = 0; nt < 4; ++nt) {
                int cg = n_tile * 32 + w * 4 + nt;
                int ksg = k0i * 2 + ks;
                bfr[nt] = *(const bf16x8*)&W2pk[((size_t)(cg * 16 + ksg) * 64 + lane) * 8];
            }
#pragma unroll
            for (int mt = 0; mt < 8; ++mt) {
                bf16x8 af = *(const bf16x8*)&As[(mt * 16 + l16) * LDA + ks * 32 + quad * 8];
#pragma unroll
                for (int nt = 0; nt < 4; ++nt)
                    acc[mt][nt] = __builtin_amdgcn_mfma_f32_16x16x32_bf16(af, bfr[nt], acc[mt][nt], 0, 0, 0);
            }
        }
        __syncthreads();
    }

    // ---- max over j: rows il*32..il*32+31 live in acc[2il..2il+1] x quad lanes ----
#pragma unroll
    for (int il = 0; il < 4; ++il)
#pragma unroll
    for (int nt = 0; nt < 4; ++nt) {
        float u = -1e30f;
#pragma unroll
        for (int p = 0; p < 2; ++p)
#pragma unroll
            for (int r = 0; r < 4; ++r) u = fmaxf(u, acc[il * 2 + p][nt][r]);
        u = fmaxf(u, __shfl_xor(u, 16));
        u = fmaxf(u, __shfl_xor(u, 32));
        if (lane < 16) {
            int col = n0 + w * 64 + nt * 16 + l16;
            int gu = m_tile * 4 + il;
            Abf[(size_t)gu * AK + H + col] = f2bf(fmaxf(u + b2[col], 0.f));
        }
    }
}

// ---------------------------------------------------------------- launch
extern "C" void kernel_launch(void* const* d_in, const int* in_sizes, int n_in,
                              void* d_out, int out_size, void* d_ws, size_t ws_size,
                              hipStream_t stream)
{
    const float* last_pos     = (const float*)d_in[0];
    const float* last_pos_rel = (const float*)d_in[1];
    const float* hh           = (const float*)d_in[2];
    const float* ch           = (const float*)d_in[3];
    const float* ptr_rel      = (const float*)d_in[4];
    const float* Wih  = (const float*)d_in[6];
    const float* Whh  = (const float*)d_in[7];
    const float* bih  = (const float*)d_in[8];
    const float* bhh  = (const float*)d_in[9];
    const float* Wse  = (const float*)d_in[10];
    const float* bse  = (const float*)d_in[11];
    const float* Wpos = (const float*)d_in[12];
    const float* bpos = (const float*)d_in[13];
    const float* Wp   = (const float*)d_in[14];
    const float* bp   = (const float*)d_in[15];
    const float* W1   = (const float*)d_in[16];
    const float* b1   = (const float*)d_in[17];
    const float* W2   = (const float*)d_in[18];
    const float* b2   = (const float*)d_in[19];
    const float* Wm1  = (const float*)d_in[20];
    const float* bm1  = (const float*)d_in[21];
    const float* Wm2  = (const float*)d_in[22];
    const float* bm2  = (const float*)d_in[23];

    float* ws     = (float*)d_ws;
    float* hbuf   = ws;                       // 65536
    float* cbuf   = hbuf + BATCH * H;         // 65536
    float* pos    = cbuf + BATCH * H;         // 1024 (padded)
    float* Hpartf = pos + 1024;               // 262144
    float* Wcx    = Hpartf + BATCH * PRE;     // 512
    float* Wcy    = Wcx + PRE;                // 512
    float* biash  = Wcy + PRE;                // 512
    float* bx     = biash + PRE;              // 512
    float* Wx0    = bx + 512;                 // 512
    float* Wx1    = Wx0 + 512;                // 512
    unsigned short* ub    = (unsigned short*)(Wx1 + 512);
    unsigned short* Abf   = ub;                         // 512*1152
    unsigned short* dhbf  = Abf + (size_t)BATCH * AK;   // 512*1024
    unsigned short* W2pk  = dhbf + (size_t)BATCH * MLPD;
    unsigned short* Wm1b  = W2pk + (size_t)BOT * PRE;
    unsigned short* Wm2b  = Wm1b + (size_t)MLPD * AK;
    unsigned short* W1pk  = Wm2b + (size_t)H * MLPD;    // 512*128 (packed)
    unsigned short* Whpk  = W1pk + (size_t)PRE * H;     // 512*128 (packed)

    float* out  = (float*)d_out;
    float* loss = out + SEQ * BATCH * 2;

    prep_kernel<<<(PREP_TOT + 255) / 256, 256, 0, stream>>>(
        W2, Wm1, Wm2, W1, Wp, bp, b1, ch, hh, last_pos, Wih, Whh, bih, bhh, Wse, bse,
        W2pk, Wm1b, Wm2b, W1pk, Wcx, Wcy, biash, cbuf, hbuf, pos, Whpk, Wx0, Wx1, bx, loss);

    for (int t = 0; t < SEQ; t++) {
        const float* relin = (t == 0) ? last_pos_rel : (ptr_rel + (t - 1) * BATCH * 2);
        const float* gt = ptr_rel + t * BATCH * 2;
        // fused LSTM gates (MFMA, K=128, packed-B) + Hpart (MFMA, packed-B) + rel_pos/loss
        lstm_hpart<<<BATCH / LROWS, 512, 0, stream>>>(t, relin, gt, Whpk, Wx0, Wx1, bx,
                                                      Wpos, bpos, W1pk, biash, hbuf, cbuf,
                                                      Abf, Hpartf, pos,
                                                      out + t * BATCH * 2, loss);
        if (t == SEQ - 1) break;   // h after last step is dead
        // fused x1-build + pool GEMM + max_j — R9: BN=512, packed-B direct (no Bs LDS)
        pool_fused<<<dim3(2, 128), 512, 0, stream>>>(Hpartf, pos, Wcx, Wcy, W2pk, b2, Abf);
        // dh = bf16(relu([h|pool] @ Wm1^T + bm1)) — 2-way split-K
        gemm_splitk<64, 32, 2, 2, 1><<<dim3(MLPD / 32, BATCH / 64), 256, 0, stream>>>(
            Abf, AK, Wm1b, AK, AK, bm1, nullptr, dhbf, MLPD);
        // h = relu(dh @ Wm2^T + bm2) -> fp32 hbuf — 4-way split-K, BM=16
        gemm_splitk<16, 32, 4, 1, 2><<<dim3(H / 32, BATCH / 16), 256, 0, stream>>>(
            dhbf, MLPD, Wm2b, MLPD, MLPD, bm2, hbuf, nullptr, H);
    }
}

// Round 10
// 714.749 us; speedup vs baseline: 1.5636x; 1.0225x over previous
//
#include <hip/hip_runtime.h>
#include <math.h>

#define BATCH 512
#define NG 16
#define GSZ 32
#define H 128
#define E 64
#define PRE 512
#define BOT 1024
#define MLPD 1024
#define SEQ 12
#define AK 1152   // Abf row length = H + BOT

typedef __attribute__((ext_vector_type(8))) short bf16x8;
typedef __attribute__((ext_vector_type(4))) float f32x4;

union bf8pack { ushort s[8]; uint4 v; };

__device__ __forceinline__ unsigned short f2bf(float f) {
    unsigned u = __float_as_uint(f);
    u += 0x7FFF + ((u >> 16) & 1);   // round-to-nearest-even
    return (unsigned short)(u >> 16);
}
__device__ __forceinline__ float bf2f(unsigned short s) {
    return __uint_as_float(((unsigned)s) << 16);
}

#define GLB(p) ((const __attribute__((address_space(1))) unsigned int*)(p))
#define LDS(p) ((__attribute__((address_space(3))) unsigned int*)(p))

// ---------------------------------------------------------------- one-shot prep
#define N0 (BOT * PRE)        /* W2pk: MFMA-fragment-packed W2 (R9) */
#define N1 (MLPD * AK)        /* Wm1pk: MFMA-fragment-packed Wm1 (R10, layout from R7) */
#define N2 (H * MLPD)         /* Wm2pk: MFMA-fragment-packed Wm2 (R10, layout from R7) */
#define N3 (PRE * H)          /* W1pk: MFMA-fragment-packed W1[:,64:192] (R4) */
#define N4 (PRE)              /* wc    */
#define N5 (BATCH * H)        /* c     */
#define N5b (BATCH * H)       /* h0 = hh */
#define N6 (BATCH * 2)        /* pos   */
#define N7 (512 * 128)        /* Whpk: MFMA-fragment-packed Whh (R4) */
#define N8 (512)              /* Wx0/Wx1/bx: rank-2 fold of dec_in@Wih^T (R3) */
#define PREP_TOT (N0 + N1 + N2 + N3 + N4 + N5 + N5b + N6 + N7 + N8 + 1)

__global__ void prep_kernel(
    const float* __restrict__ W2, const float* __restrict__ Wm1,
    const float* __restrict__ Wm2, const float* __restrict__ W1,
    const float* __restrict__ Wp, const float* __restrict__ bp, const float* __restrict__ b1,
    const float* __restrict__ ch, const float* __restrict__ hh, const float* __restrict__ last_pos,
    const float* __restrict__ Wih, const float* __restrict__ Whh,
    const float* __restrict__ bih, const float* __restrict__ bhh,
    const float* __restrict__ Wse, const float* __restrict__ bse,
    unsigned short* __restrict__ W2pk, unsigned short* __restrict__ Wm1pk,
    unsigned short* __restrict__ Wm2pk, unsigned short* __restrict__ W1pk,
    float* __restrict__ Wcx, float* __restrict__ Wcy, float* __restrict__ biash,
    float* __restrict__ cbuf, float* __restrict__ hbuf, float* __restrict__ pos,
    unsigned short* __restrict__ Whpk,
    float* __restrict__ Wx0, float* __restrict__ Wx1, float* __restrict__ bx,
    float* __restrict__ loss)
{
    long idx = (long)blockIdx.x * 256 + threadIdx.x;
    if (idx < N0) {
        // W2pk[((cg*16+ksg)*64 + lane)*8 + e] = W2[col*512 + kk]
        //   col = cg*16 + (lane&15), kk = ksg*32 + (lane>>4)*8 + e
        int e = (int)(idx & 7);
        long u = idx >> 3;
        int lane = (int)(u & 63);
        int rest = (int)(u >> 6);            // 0 .. 1023
        int ksg = rest & 15, cg = rest >> 4; // cg 0..63
        int col = cg * 16 + (lane & 15);
        int kk = ksg * 32 + (lane >> 4) * 8 + e;
        W2pk[idx] = f2bf(W2[(size_t)col * PRE + kk]);
        return;
    }
    idx -= N0;
    if (idx < N1) {
        // Wm1pk[((cg*36+ksg)*64+lane)*8+e] = Wm1[col*1152 + k]
        //   col = cg*16 + (lane&15), k = ksg*32 + (lane>>4)*8 + e   (cg 0..63, ksg 0..35)
        int e = (int)(idx & 7);
        long u = idx >> 3;
        int lane = (int)(u & 63);
        long rest = u >> 6;                 // 0 .. 2303
        int ksg = (int)(rest % 36);
        int cg = (int)(rest / 36);          // 0 .. 63
        int col = cg * 16 + (lane & 15);
        int k = ksg * 32 + (lane >> 4) * 8 + e;
        Wm1pk[idx] = f2bf(Wm1[(size_t)col * AK + k]);
        return;
    }
    idx -= N1;
    if (idx < N2) {
        // Wm2pk[((cg*32+ksg)*64+lane)*8+e] = Wm2[col*1024 + k]
        //   col = cg*16 + (lane&15), k = ksg*32 + (lane>>4)*8 + e   (cg 0..7, ksg 0..31)
        int e = (int)(idx & 7);
        long u = idx >> 3;
        int lane = (int)(u & 63);
        int rest = (int)(u >> 6);           // 0 .. 255
        int ksg = rest & 31, cg = rest >> 5;
        int col = cg * 16 + (lane & 15);
        int k = ksg * 32 + (lane >> 4) * 8 + e;
        Wm2pk[idx] = f2bf(Wm2[(size_t)col * MLPD + k]);
        return;
    }
    idx -= N2;
    if (idx < N3) {
        // W1pk[(((w*4+ks)*4+nt)*4+quad)*16 + l16][e] = W1[col*192 + 64 + k]
        int e = (int)(idx & 7);
        int u = (int)(idx >> 3);
        int l16 = u & 15, quad = (u >> 4) & 3, nt = (u >> 6) & 3, ks = (u >> 8) & 3, w = u >> 10;
        int col = w * 64 + nt * 16 + l16;
        int k = ks * 32 + quad * 8 + e;
        W1pk[idx] = f2bf(W1[col * 192 + E + k]);
        return;
    }
    idx -= N3;
    if (idx < N4) {
        int p = (int)idx;
        float sx = 0.f, sy = 0.f, sb = 0.f;
#pragma unroll 8
        for (int e = 0; e < E; ++e) {
            float w = W1[p * 192 + e];
            sx += w * Wp[e * 2 + 0];
            sy += w * Wp[e * 2 + 1];
            sb += w * bp[e];
        }
        Wcx[p] = sx; Wcy[p] = sy; biash[p] = b1[p] + sb;
        return;
    }
    idx -= N4;
    if (idx < N5) { cbuf[idx] = ch[idx]; return; }
    idx -= N5;
    if (idx < N5b) { hbuf[idx] = hh[idx]; return; }
    idx -= N5b;
    if (idx < N6) { pos[idx] = last_pos[idx]; return; }
    idx -= N6;
    if (idx < N7) {
        // Whpk[(((g*8+w)*4+ks)*4+quad)*16 + l16][e] = Whh[col*128 + k]
        int e = (int)(idx & 7);
        int u = (int)(idx >> 3);
        int l16 = u & 15, quad = (u >> 4) & 3, ks = (u >> 6) & 3, w = (u >> 8) & 7, g = u >> 11;
        int col = g * 128 + w * 16 + l16;
        int k = ks * 32 + quad * 8 + e;
        Whpk[idx] = f2bf(Whh[col * H + k]);
        return;
    }
    idx -= N7;
    if (idx < N8) {
        int u = (int)idx;
        float sx = 0.f, sy = 0.f, sb = 0.f;
#pragma unroll 8
        for (int e = 0; e < E; ++e) {
            float w = Wih[u * E + e];
            sx += w * Wse[e * 2 + 0];
            sy += w * Wse[e * 2 + 1];
            sb += w * bse[e];
        }
        Wx0[u] = sx; Wx1[u] = sy; bx[u] = sb + bih[u] + bhh[u];
        return;
    }
    idx -= N8;
    if (idx == 0) *loss = 0.0f;
}

// ---------------------------------------------------------------- fused LSTM + Hpart
// R2: 32 blocks x 512 threads, 16 rows/block, 8 waves.
// R3: dec_in@Wih^T folded to rank-2 -> gate GEMM K=128.
// R4: B-operands pre-packed in MFMA fragment order (base + lane*16B loads).
// R10: block-level loss reduction -> 1 atomicAdd/block (was 32; 1024 same-address
//      atomics per dispatch serialized at L2 — Guideline 12).
#define LROWS 16
__global__ __launch_bounds__(512) void lstm_hpart(
    int t,
    const float* __restrict__ relin, const float* __restrict__ gt,
    const unsigned short* __restrict__ Whpk,
    const float* __restrict__ Wx0, const float* __restrict__ Wx1, const float* __restrict__ bx,
    const float* __restrict__ Wpos, const float* __restrict__ bpos,
    const unsigned short* __restrict__ W1pk, const float* __restrict__ biash,
    const float* __restrict__ hbuf, float* __restrict__ cbuf,
    unsigned short* __restrict__ Abf, float* __restrict__ Hpartf,
    float* __restrict__ pos, float* __restrict__ traj, float* __restrict__ loss)
{
    constexpr int LDHB = 136;
    constexpr int LDHF = 129;
    __shared__ __align__(16) unsigned short As[LROWS * LDHB];
    __shared__ __align__(16) unsigned short hnb[LROWS * LDHB];
    __shared__ float hnf[LROWS * LDHF];
    __shared__ float lred[8];
    const int r0 = blockIdx.x * LROWS;     // global row base
    const int tid = threadIdx.x;
    const int lane = tid & 63, w = tid >> 6;          // w in 0..7
    const int quad = lane >> 4, l16 = lane & 15;

    // ---- build A = bf16(h_in) : 16 x 128 ----
    for (int idx = tid; idx < LROWS * H; idx += 512) {
        int row = idx >> 7, k = idx & 127;
        As[row * LDHB + k] = f2bf(hbuf[(size_t)(r0 + row) * H + k]);
    }
    __syncthreads();

    // ---- gate GEMM (K=128): wave w -> u-slice [w*16, w*16+16), all 4 gates ----
    f32x4 acc[4];
#pragma unroll
    for (int g4 = 0; g4 < 4; ++g4) acc[g4] = (f32x4)0.f;
#pragma unroll
    for (int ks = 0; ks < 4; ++ks) {
        bf16x8 af = *(const bf16x8*)&As[l16 * LDHB + ks * 32 + quad * 8];
#pragma unroll
        for (int gate = 0; gate < 4; ++gate) {
            bf16x8 bf = *(const bf16x8*)&Whpk[((size_t)((gate * 8 + w) * 4 + ks) * 64 + lane) * 8];
            acc[gate] = __builtin_amdgcn_mfma_f32_16x16x32_bf16(af, bf, acc[gate], 0, 0, 0);
        }
    }

    // ---- nonlinearity + c update (u = w*16 + l16, rows = quad*4+r) ----
    {
        int u = w * 16 + l16;
        float wx0[4], wx1[4], bxv[4];
#pragma unroll
        for (int gate = 0; gate < 4; ++gate) {
            int col = gate * 128 + u;
            wx0[gate] = Wx0[col]; wx1[gate] = Wx1[col]; bxv[gate] = bx[col];
        }
#pragma unroll
        for (int r = 0; r < 4; ++r) {
            int row = quad * 4 + r;
            int b = r0 + row;
            float rx = relin[b * 2 + 0], ry = relin[b * 2 + 1];
            float i_ = acc[0][r] + rx * wx0[0] + ry * wx1[0] + bxv[0];
            float f_ = acc[1][r] + rx * wx0[1] + ry * wx1[1] + bxv[1];
            float g_ = acc[2][r] + rx * wx0[2] + ry * wx1[2] + bxv[2];
            float o_ = acc[3][r] + rx * wx0[3] + ry * wx1[3] + bxv[3];
            float ig = 1.0f / (1.0f + expf(-i_));
            float fg = 1.0f / (1.0f + expf(-f_));
            float gg = tanhf(g_);
            float og = 1.0f / (1.0f + expf(-o_));
            float c = fg * cbuf[(size_t)b * H + u] + ig * gg;
            cbuf[(size_t)b * H + u] = c;
            float h = og * tanhf(c);
            hnb[row * LDHB + u] = f2bf(h);
            hnf[row * LDHF + u] = h;
            Abf[(size_t)b * AK + u] = f2bf(h);
        }
    }
    __syncthreads();

    // ---- Hpart GEMM (dead at last step): wave w -> cols [w*64, w*64+64) ----
    if (t < SEQ - 1) {
        f32x4 acc2[4];
#pragma unroll
        for (int nt = 0; nt < 4; ++nt) acc2[nt] = (f32x4)0.f;
#pragma unroll
        for (int ks = 0; ks < 4; ++ks) {
            bf16x8 af = *(const bf16x8*)&hnb[l16 * LDHB + ks * 32 + quad * 8];
#pragma unroll
            for (int nt = 0; nt < 4; ++nt) {
                bf16x8 bfr = *(const bf16x8*)&W1pk[((size_t)((w * 4 + ks) * 4 + nt) * 64 + lane) * 8];
                acc2[nt] = __builtin_amdgcn_mfma_f32_16x16x32_bf16(af, bfr, acc2[nt], 0, 0, 0);
            }
        }
#pragma unroll
        for (int nt = 0; nt < 4; ++nt) {
            int col = w * 64 + nt * 16 + l16;
            float bv = biash[col];
#pragma unroll
            for (int r = 0; r < 4; ++r) {
                int row = quad * 4 + r;
                Hpartf[(size_t)(r0 + row) * PRE + col] = acc2[nt][r] + bv;
            }
        }
    }

    // ---- rel_pos / curr_pos / traj / loss — 512 threads, 16-seg shfl reduce ----
    {
        int row = tid >> 5, o = (tid >> 4) & 1, seg = tid & 15;
        const float* wr = Wpos + o * H + seg * 8;
        const float* hr = &hnf[row * LDHF + seg * 8];
        float acc3 = 0.f;
#pragma unroll
        for (int k = 0; k < 8; ++k) acc3 += wr[k] * hr[k];
        acc3 += __shfl_xor(acc3, 1);
        acc3 += __shfl_xor(acc3, 2);
        acc3 += __shfl_xor(acc3, 4);
        acc3 += __shfl_xor(acc3, 8);
        // after butterfly all 16 lanes of the group hold the full dot product
        acc3 += bpos[o];
        int b = r0 + row;
        float d = acc3 - gt[b * 2 + o];
        if (seg == 0) {
            float lp = pos[b * 2 + o];
            pos[b * 2 + o] = acc3 + lp;
            traj[b * 2 + o] = acc3;
        }
        // block-level loss reduce: 4 contributions/wave -> 1 atomic/block
        float part = (seg == 0) ? d * d : 0.f;
        part += __shfl_xor(part, 16);
        part += __shfl_xor(part, 32);
        if (lane == 0) lred[w] = part;
        __syncthreads();
        if (tid == 0) {
            float s = 0.f;
#pragma unroll
            for (int i = 0; i < 8; ++i) s += lred[i];
            atomicAdd(loss, s * (1.0f / 1024.0f));
        }
    }
}

// ---------------------------------------------------------------- split-K bf16 MFMA GEMM, packed-B (R10)
// C = A(MxK) @ Bpk^T; 256 thr = 4 waves; wave w: kslice = w/NW, nslice = w%NW.
// B fragments loaded directly from fragment-packed global (base + lane*16B,
// L2-resident) — no Bs LDS (R8 counters: 128B-stride LDS rows = 16-way conflicts).
// MODE 1: Cb = bf16(relu(acc+bias)) | MODE 2: Cf = relu(acc+bias)
template <int BM, int BN, int KW, int NW, int MODE>
__global__ __launch_bounds__(256) void gemm_splitk_pk(
    const unsigned short* __restrict__ A, int lda,
    const unsigned short* __restrict__ Bpk, int K,
    const float* __restrict__ bias,
    float* __restrict__ Cf, unsigned short* __restrict__ Cb, int ldc)
{
    constexpr int MT = BM / 16;            // A frags per wave
    constexpr int NT = BN / (16 * NW);     // B frags per wave
    __shared__ __align__(16) unsigned short As[KW * BM * 64];
    __shared__ float red[KW * BM * BN];
    int tid = threadIdx.x;
    int lane = tid & 63, w = tid >> 6;
    int kslice = w / NW, nslice = w % NW;
    int gtid = tid & (NW * 64 - 1);
    int quad = lane >> 4, l16 = lane & 15;
    int m0 = blockIdx.y * BM, n0 = blockIdx.x * BN;
    const int KC = K / KW;                 // K per slice (multiple of 64)
    const int KSGT = K >> 5;               // total 32-wide k-groups in packed B
    const int cgbase = (n0 + nslice * (BN / NW)) >> 4;

    f32x4 acc[MT][NT];
#pragma unroll
    for (int mt = 0; mt < MT; ++mt)
#pragma unroll
        for (int nt = 0; nt < NT; ++nt) acc[mt][nt] = (f32x4)0.f;

    for (int k0 = 0; k0 < KC; k0 += 64) {
        int kb = kslice * KC + k0;
        int kgbase = kb >> 5;
#pragma unroll
        for (int u = 0; u < BM / (8 * NW); ++u) {
            int c = u * NW * 64 + gtid;
            __builtin_amdgcn_global_load_lds(
                GLB(A + (size_t)(m0 + (c >> 3)) * lda + kb + (c & 7) * 8),
                LDS(&As[kslice * BM * 64 + c * 8]), 16, 0, 0);
        }
        __syncthreads();
#pragma unroll
        for (int ks = 0; ks < 2; ++ks) {
            bf16x8 af[MT], bfr[NT];
#pragma unroll
            for (int mt = 0; mt < MT; ++mt)
                af[mt] = *(const bf16x8*)&As[kslice * BM * 64 + (mt * 16 + l16) * 64 + ks * 32 + quad * 8];
#pragma unroll
            for (int nt = 0; nt < NT; ++nt)
                bfr[nt] = *(const bf16x8*)&Bpk[((size_t)((cgbase + nt) * KSGT + kgbase + ks) * 64 + lane) * 8];
#pragma unroll
            for (int mt = 0; mt < MT; ++mt)
#pragma unroll
                for (int nt = 0; nt < NT; ++nt)
                    acc[mt][nt] = __builtin_amdgcn_mfma_f32_16x16x32_bf16(af[mt], bfr[nt], acc[mt][nt], 0, 0, 0);
        }
        __syncthreads();
    }

    // ---- partials -> LDS ----
#pragma unroll
    for (int mt = 0; mt < MT; ++mt)
#pragma unroll
    for (int nt = 0; nt < NT; ++nt) {
#pragma unroll
        for (int r = 0; r < 4; ++r) {
            int row = mt * 16 + quad * 4 + r;
            int col = nslice * (BN / NW) + nt * 16 + l16;
            red[kslice * BM * BN + row * BN + col] = acc[mt][nt][r];
        }
    }
    __syncthreads();

    // ---- reduce KW partials + bias + relu + store ----
#pragma unroll
    for (int o = 0; o < BM * BN / 256; ++o) {
        int e = o * 256 + tid;
        int row = e / BN, col = e % BN;
        float s = 0.f;
#pragma unroll
        for (int k = 0; k < KW; ++k) s += red[k * BM * BN + e];
        float v = fmaxf(s + bias[n0 + col], 0.f);
        if (MODE == 1) Cb[(size_t)(m0 + row) * ldc + n0 + col] = f2bf(v);
        else           Cf[(size_t)(m0 + row) * ldc + n0 + col] = v;
    }
}

// ---------------------------------------------------------------- fused x1-build + pool GEMM + max_j
// R5/R6: A-tile built in LDS from Hpart/pos/Wc* each K-step, BN=512.
// R9: B read directly from fragment-packed W2pk (no Bs LDS, no bank conflicts).
__global__ __launch_bounds__(512) void pool_fused(
    const float* __restrict__ Hpartf, const float* __restrict__ pos,
    const float* __restrict__ Wcx, const float* __restrict__ Wcy,
    const unsigned short* __restrict__ W2pk,
    const float* __restrict__ b2, unsigned short* __restrict__ Abf)
{
    constexpr int BN = 512;
    constexpr int LDA = 72;    // pad: row stride 144B -> 2-way bank aliasing (free, m136)
    __shared__ __align__(16) unsigned short As[128 * LDA];   // 18 KB
    const int tid = threadIdx.x;
    const int lane = tid & 63, w = tid >> 6;       // 8 waves
    const int quad = lane >> 4, l16 = lane & 15;
    const int n_tile = blockIdx.x, m_tile = blockIdx.y;
    const int g = m_tile >> 3, iq = m_tile & 7;
    const int n0 = n_tile * BN;

    // per-thread build coords (loop-invariant): thread -> (row, 16-col slab)
    const int brow = tid >> 2;                 // 0..127
    const int k8 = (tid & 3) * 16;             // col base within K-step
    const int bi = iq * 4 + (brow >> 5), bj = brow & 31;
    const float rx = pos[(g * GSZ + bj) * 2 + 0] - pos[(g * GSZ + bi) * 2 + 0];
    const float ry = pos[(g * GSZ + bj) * 2 + 1] - pos[(g * GSZ + bi) * 2 + 1];
    const float* hrow = &Hpartf[(size_t)(g * GSZ + bj) * PRE];

    f32x4 acc[8][4];
#pragma unroll
    for (int mt = 0; mt < 8; ++mt)
#pragma unroll
        for (int nt = 0; nt < 4; ++nt) acc[mt][nt] = (f32x4)0.f;

    for (int k0i = 0; k0i < 8; ++k0i) {
        const int k0 = k0i * 64;
        // build A: As[row][kk] = bf16(relu(Hpart[j][k0+kk] + rx*Wcx + ry*Wcy))
        {
            const float4* hp = (const float4*)(hrow + k0 + k8);
            const float4* wx = (const float4*)(Wcx + k0 + k8);
            const float4* wy = (const float4*)(Wcy + k0 + k8);
            bf8pack o[2];
#pragma unroll
            for (int q = 0; q < 2; ++q) {
                float4 ha = hp[q * 2], hb = hp[q * 2 + 1];
                float4 xa = wx[q * 2], xb = wx[q * 2 + 1];
                float4 ya = wy[q * 2], yb = wy[q * 2 + 1];
                o[q].s[0] = f2bf(fmaxf(ha.x + rx * xa.x + ry * ya.x, 0.f));
                o[q].s[1] = f2bf(fmaxf(ha.y + rx * xa.y + ry * ya.y, 0.f));
                o[q].s[2] = f2bf(fmaxf(ha.z + rx * xa.z + ry * ya.z, 0.f));
                o[q].s[3] = f2bf(fmaxf(ha.w + rx * xa.w + ry * ya.w, 0.f));
                o[q].s[4] = f2bf(fmaxf(hb.x + rx * xb.x + ry * yb.x, 0.f));
                o[q].s[5] = f2bf(fmaxf(hb.y + rx * xb.y + ry * yb.y, 0.f));
                o[q].s[6] = f2bf(fmaxf(hb.z + rx * xb.z + ry * yb.z, 0.f));
                o[q].s[7] = f2bf(fmaxf(hb.w + rx * xb.w + ry * yb.w, 0.f));
            }
            *(uint4*)&As[brow * LDA + k8] = o[0].v;
            *(uint4*)&As[brow * LDA + k8 + 8] = o[1].v;
        }
        __syncthreads();
#pragma unroll
        for (int ks = 0; ks < 2; ++ks) {
            // B fragments direct from packed global: cg = n0/16 + w*4 + nt, ksg = k0/32 + ks
            bf16x8 bfr[4];
#pragma unroll
            for (int nt = 0; nt < 4; ++nt) {
                int cg = n_tile * 32 + w * 4 + nt;
                int ksg = k0i * 2 + ks;
                bfr[nt] = *(const bf16x8*)&W2pk[((size_t)(cg * 16 + ksg) * 64 + lane) * 8];
            }
#pragma unroll
            for (int mt = 0; mt < 8; ++mt) {
                bf16x8 af = *(const bf16x8*)&As[(mt * 16 + l16) * LDA + ks * 32 + quad * 8];
#pragma unroll
                for (int nt = 0; nt < 4; ++nt)
                    acc[mt][nt] = __builtin_amdgcn_mfma_f32_16x16x32_bf16(af, bfr[nt], acc[mt][nt], 0, 0, 0);
            }
        }
        __syncthreads();
    }

    // ---- max over j: rows il*32..il*32+31 live in acc[2il..2il+1] x quad lanes ----
#pragma unroll
    for (int il = 0; il < 4; ++il)
#pragma unroll
    for (int nt = 0; nt < 4; ++nt) {
        float u = -1e30f;
#pragma unroll
        for (int p = 0; p < 2; ++p)
#pragma unroll
            for (int r = 0; r < 4; ++r) u = fmaxf(u, acc[il * 2 + p][nt][r]);
        u = fmaxf(u, __shfl_xor(u, 16));
        u = fmaxf(u, __shfl_xor(u, 32));
        if (lane < 16) {
            int col = n0 + w * 64 + nt * 16 + l16;
            int gu = m_tile * 4 + il;
            Abf[(size_t)gu * AK + H + col] = f2bf(fmaxf(u + b2[col], 0.f));
        }
    }
}

// ---------------------------------------------------------------- launch
extern "C" void kernel_launch(void* const* d_in, const int* in_sizes, int n_in,
                              void* d_out, int out_size, void* d_ws, size_t ws_size,
                              hipStream_t stream)
{
    const float* last_pos     = (const float*)d_in[0];
    const float* last_pos_rel = (const float*)d_in[1];
    const float* hh           = (const float*)d_in[2];
    const float* ch           = (const float*)d_in[3];
    const float* ptr_rel      = (const float*)d_in[4];
    const float* Wih  = (const float*)d_in[6];
    const float* Whh  = (const float*)d_in[7];
    const float* bih  = (const float*)d_in[8];
    const float* bhh  = (const float*)d_in[9];
    const float* Wse  = (const float*)d_in[10];
    const float* bse  = (const float*)d_in[11];
    const float* Wpos = (const float*)d_in[12];
    const float* bpos = (const float*)d_in[13];
    const float* Wp   = (const float*)d_in[14];
    const float* bp   = (const float*)d_in[15];
    const float* W1   = (const float*)d_in[16];
    const float* b1   = (const float*)d_in[17];
    const float* W2   = (const float*)d_in[18];
    const float* b2   = (const float*)d_in[19];
    const float* Wm1  = (const float*)d_in[20];
    const float* bm1  = (const float*)d_in[21];
    const float* Wm2  = (const float*)d_in[22];
    const float* bm2  = (const float*)d_in[23];

    float* ws     = (float*)d_ws;
    float* hbuf   = ws;                       // 65536
    float* cbuf   = hbuf + BATCH * H;         // 65536
    float* pos    = cbuf + BATCH * H;         // 1024 (padded)
    float* Hpartf = pos + 1024;               // 262144
    float* Wcx    = Hpartf + BATCH * PRE;     // 512
    float* Wcy    = Wcx + PRE;                // 512
    float* biash  = Wcy + PRE;                // 512
    float* bx     = biash + PRE;              // 512
    float* Wx0    = bx + 512;                 // 512
    float* Wx1    = Wx0 + 512;                // 512
    unsigned short* ub    = (unsigned short*)(Wx1 + 512);
    unsigned short* Abf   = ub;                         // 512*1152
    unsigned short* dhbf  = Abf + (size_t)BATCH * AK;   // 512*1024
    unsigned short* W2pk  = dhbf + (size_t)BATCH * MLPD;
    unsigned short* Wm1pk = W2pk + (size_t)BOT * PRE;
    unsigned short* Wm2pk = Wm1pk + (size_t)MLPD * AK;
    unsigned short* W1pk  = Wm2pk + (size_t)H * MLPD;   // 512*128 (packed)
    unsigned short* Whpk  = W1pk + (size_t)PRE * H;     // 512*128 (packed)

    float* out  = (float*)d_out;
    float* loss = out + SEQ * BATCH * 2;

    prep_kernel<<<(PREP_TOT + 255) / 256, 256, 0, stream>>>(
        W2, Wm1, Wm2, W1, Wp, bp, b1, ch, hh, last_pos, Wih, Whh, bih, bhh, Wse, bse,
        W2pk, Wm1pk, Wm2pk, W1pk, Wcx, Wcy, biash, cbuf, hbuf, pos, Whpk, Wx0, Wx1, bx, loss);

    for (int t = 0; t < SEQ; t++) {
        const float* relin = (t == 0) ? last_pos_rel : (ptr_rel + (t - 1) * BATCH * 2);
        const float* gt = ptr_rel + t * BATCH * 2;
        // fused LSTM gates (MFMA, K=128, packed-B) + Hpart (MFMA, packed-B) + rel_pos/loss
        lstm_hpart<<<BATCH / LROWS, 512, 0, stream>>>(t, relin, gt, Whpk, Wx0, Wx1, bx,
                                                      Wpos, bpos, W1pk, biash, hbuf, cbuf,
                                                      Abf, Hpartf, pos,
                                                      out + t * BATCH * 2, loss);
        if (t == SEQ - 1) break;   // h after last step is dead
        // fused x1-build + pool GEMM + max_j — BN=512, packed-B direct (no Bs LDS)
        pool_fused<<<dim3(2, 128), 512, 0, stream>>>(Hpartf, pos, Wcx, Wcy, W2pk, b2, Abf);
        // dh = bf16(relu([h|pool] @ Wm1^T + bm1)) — 2-way split-K, packed-B direct (R10)
        gemm_splitk_pk<64, 32, 2, 2, 1><<<dim3(MLPD / 32, BATCH / 64), 256, 0, stream>>>(
            Abf, AK, Wm1pk, AK, bm1, nullptr, dhbf, MLPD);
        // h = relu(dh @ Wm2^T + bm2) -> fp32 hbuf — 4-way split-K, packed-B direct (R10)
        gemm_splitk_pk<16, 32, 4, 1, 2><<<dim3(H / 32, BATCH / 16), 256, 0, stream>>>(
            dhbf, MLPD, Wm2pk, MLPD, bm2, hbuf, nullptr, H);
    }
}